// Round 12
// baseline (1551.153 us; speedup 1.0000x reference)
//
#include <hip/hip_runtime.h>
#include <cstdint>

// B=2, S=512, D=1024, H=16, HD=64, L=12, V=50257, DFF=4096

typedef __bf16 bf16x8 __attribute__((ext_vector_type(8)));
typedef __bf16 bf16x4 __attribute__((ext_vector_type(4)));
typedef float  f32x4  __attribute__((ext_vector_type(4)));

#define GLDS16(g, l) __builtin_amdgcn_global_load_lds( \
    (const __attribute__((address_space(1))) unsigned int*)(g), \
    (__attribute__((address_space(3))) unsigned int*)(l), 16, 0, 0)

#define SCHED_FENCE() __builtin_amdgcn_sched_barrier(0)

__device__ __forceinline__ float gelu_f(float x) {
    float u = 1.5957691216057308f * (x + 0.044715f * x * x * x);
    float e = __expf(u);
    float t = 1.0f - 2.0f / (e + 1.0f);
    return 0.5f * x * (1.0f + t);
}

// swizzled fragment offset in a [rows][64] bf16 LDS tile (T2 XOR, pairs with staging perm)
__device__ __forceinline__ int fragoff(int row, int kh, int hi) {
    return row * 64 + ((kh * 32 + hi * 8) ^ ((row & 7) << 3));
}

// ---------- weight transpose+convert body: 64x64 f32 tile -> bf16 [N][K] ----------
__device__ __forceinline__ void tcvt_body(
    int id, const float* __restrict__ Wa, const float* __restrict__ Wp,
    const float* __restrict__ Wf, const float* __restrict__ Wf2,
    __bf16* __restrict__ oa, __bf16* __restrict__ op,
    __bf16* __restrict__ of, __bf16* __restrict__ of2, float* tile)
{
    const float* src; __bf16* dst; int K, N, kb, nb;
    if (id < 768)       { src = Wa;  dst = oa;  K = 1024; N = 3072; kb = id & 15; nb = id >> 4; }
    else if (id < 1024) { id -= 768;  src = Wp;  dst = op;  K = 1024; N = 1024; kb = id & 15; nb = id >> 4; }
    else if (id < 2048) { id -= 1024; src = Wf;  dst = of;  K = 1024; N = 4096; kb = id & 15; nb = id >> 4; }
    else                { id -= 2048; src = Wf2; dst = of2; K = 4096; N = 1024; kb = id & 63; nb = id >> 6; }
    const int k0 = kb * 64, n0 = nb * 64;
    const int t = threadIdx.x;
    #pragma unroll
    for (int i = 0; i < 4; i++) {
        int r = i * 16 + (t >> 4), c = (t & 15) * 4;
        float4 v = *reinterpret_cast<const float4*>(src + (long)(k0 + r) * N + n0 + c);
        tile[r * 65 + c] = v.x; tile[r * 65 + c + 1] = v.y;
        tile[r * 65 + c + 2] = v.z; tile[r * 65 + c + 3] = v.w;
    }
    __syncthreads();
    const int nrow = t >> 2, kc = (t & 3) * 16;
    bf16x8 o0, o1;
    #pragma unroll
    for (int i = 0; i < 8; i++) {
        o0[i] = (__bf16)tile[(kc + i) * 65 + nrow];
        o1[i] = (__bf16)tile[(kc + 8 + i) * 65 + nrow];
    }
    *reinterpret_cast<bf16x8*>(dst + (long)(n0 + nrow) * K + k0 + kc)     = o0;
    *reinterpret_cast<bf16x8*>(dst + (long)(n0 + nrow) * K + k0 + kc + 8) = o1;
}

// ---------- wte fp32 -> bf16 body ----------
__device__ __forceinline__ void wcvt_body(
    int id, const float* __restrict__ wte, __bf16* __restrict__ out, long nvalid)
{
    long base = (long)id * 8192 + threadIdx.x * 8;
    #pragma unroll
    for (int i = 0; i < 4; i++) {
        long e = base + (long)i * 2048;
        bf16x8 o;
        if (e < nvalid) {
            float4 a = *reinterpret_cast<const float4*>(wte + e);
            float4 b = *reinterpret_cast<const float4*>(wte + e + 4);
            o[0] = (__bf16)a.x; o[1] = (__bf16)a.y; o[2] = (__bf16)a.z; o[3] = (__bf16)a.w;
            o[4] = (__bf16)b.x; o[5] = (__bf16)b.y; o[6] = (__bf16)b.z; o[7] = (__bf16)b.w;
        } else {
            #pragma unroll
            for (int q = 0; q < 8; q++) o[q] = (__bf16)0.f;
        }
        *reinterpret_cast<bf16x8*>(out + e) = o;
    }
}

// ---------- embedding + layer-0 LN body ----------
__device__ __forceinline__ void embed_body(
    int row, const int* __restrict__ ids, const float* __restrict__ wte,
    float* __restrict__ h, __bf16* __restrict__ xb,
    const float* __restrict__ g, const float* __restrict__ b, float* red)
{
    int s = row & 511;
    int t = threadIdx.x;
    long id = ids[row];
    float4 v1 = reinterpret_cast<const float4*>(wte + id * 1024)[t];
    float4 v2 = reinterpret_cast<const float4*>(wte + (long)s * 1024)[t];
    float4 v; v.x = v1.x + v2.x; v.y = v1.y + v2.y; v.z = v1.z + v2.z; v.w = v1.w + v2.w;
    reinterpret_cast<float4*>(h + (long)row * 1024)[t] = v;

    float s1 = v.x + v.y + v.z + v.w;
    float s2 = v.x * v.x + v.y * v.y + v.z * v.z + v.w * v.w;
    #pragma unroll
    for (int o = 32; o >= 1; o >>= 1) { s1 += __shfl_xor(s1, o); s2 += __shfl_xor(s2, o); }
    int w = t >> 6;
    if ((t & 63) == 0) { red[w] = s1; red[4 + w] = s2; }
    __syncthreads();
    s1 = red[0] + red[1] + red[2] + red[3];
    s2 = red[4] + red[5] + red[6] + red[7];
    float mean = s1 * (1.0f / 1024.0f);
    float var  = s2 * (1.0f / 1024.0f) - mean * mean;
    float rstd = rsqrtf(var + 1e-5f);
    float4 gg = reinterpret_cast<const float4*>(g)[t];
    float4 bb = reinterpret_cast<const float4*>(b)[t];
    bf16x4 o;
    o[0] = (__bf16)((v.x - mean) * rstd * gg.x + bb.x);
    o[1] = (__bf16)((v.y - mean) * rstd * gg.y + bb.y);
    o[2] = (__bf16)((v.z - mean) * rstd * gg.z + bb.z);
    o[3] = (__bf16)((v.w - mean) * rstd * gg.w + bb.w);
    *reinterpret_cast<bf16x4*>(xb + (long)row * 1024 + t * 4) = o;
}

// ---------- ft first-layer gemv partial body (z=0, K=N=1024, ksplit-8) ----------
__device__ __forceinline__ void ftpart_body(
    int id, const float* __restrict__ x, const float* __restrict__ W,
    float* __restrict__ part, float* red)
{
    int jb = id & 15, kz = id >> 4;
    int t = threadIdx.x;
    int j = (jb << 6) + (t & 63);
    int g = t >> 6;
    int kbase = (kz * 4 + g) * 32;
    const float* Wp = W + (long)kbase * 1024 + j;
    const float* x0 = x + kbase;
    const float* x1 = x + 1024 + kbase;
    float a0 = 0.f, a1 = 0.f;
    for (int k = 0; k < 32; k++) {
        float wv = Wp[(long)k * 1024];
        a0 += x0[k] * wv;
        a1 += x1[k] * wv;
    }
    red[g * 64 + (t & 63)] = a0;
    red[256 + g * 64 + (t & 63)] = a1;
    __syncthreads();
    if (t < 64) {
        a0 = red[t] + red[64 + t] + red[128 + t] + red[192 + t];
        a1 = red[256 + t] + red[320 + t] + red[384 + t] + red[448 + t];
        long base = (long)kz * 2 * 1024 + (jb << 6) + t;
        part[base]        = a0;
        part[base + 1024] = a1;
    }
}

// ---------- pre-loop union: embed (0..1023) | tcvt layer0 (1024..4095) | ft1 part ----------
__global__ __launch_bounds__(256) void preloop0(
    const int* __restrict__ ids, const float* __restrict__ wte,
    float* __restrict__ h, __bf16* __restrict__ xb,
    const float* __restrict__ g, const float* __restrict__ b,
    const float* __restrict__ Wa, const float* __restrict__ Wp,
    const float* __restrict__ Wf, const float* __restrict__ Wf2,
    __bf16* __restrict__ oa, __bf16* __restrict__ op,
    __bf16* __restrict__ of, __bf16* __restrict__ of2,
    const float* __restrict__ ihs, const float* __restrict__ ftW1,
    float* __restrict__ part)
{
    __shared__ __align__(16) char smem[16640];
    const int bid = blockIdx.x;
    if (bid < 1024)       embed_body(bid, ids, wte, h, xb, g, b, (float*)smem);
    else if (bid < 4096)  tcvt_body(bid - 1024, Wa, Wp, Wf, Wf2, oa, op, of, of2, (float*)smem);
    else                  ftpart_body(bid - 4096, ihs, ftW1, part, (float*)smem);
}

__global__ __launch_bounds__(256) void tcvt_std(
    const float* __restrict__ Wa, const float* __restrict__ Wp,
    const float* __restrict__ Wf, const float* __restrict__ Wf2,
    __bf16* __restrict__ oa, __bf16* __restrict__ op,
    __bf16* __restrict__ of, __bf16* __restrict__ of2)
{
    __shared__ float tile[64 * 65];
    tcvt_body(blockIdx.x, Wa, Wp, Wf, Wf2, oa, op, of, of2, tile);
}

__global__ __launch_bounds__(256) void wcvt_std(
    const float* __restrict__ wte, __bf16* __restrict__ out, long nvalid)
{
    wcvt_body(blockIdx.x, wte, out, nvalid);
}

// ---------- small GEMV path (img feature transform), ksplit-8 ----------
__global__ __launch_bounds__(256) void gemv_part(
    const float* __restrict__ x, int xld,
    const float* __restrict__ W, long wzs,
    float* __restrict__ part, int K, int N)
{
    int jb = blockIdx.x, kz = blockIdx.y, z = blockIdx.z;
    int t = threadIdx.x;
    int j = (jb << 6) + (t & 63);
    int g = t >> 6;
    int klen = K / (gridDim.y * 4);
    int kbase = (kz * 4 + g) * klen;
    const float* Wp = W + (long)z * wzs + (long)kbase * N + j;
    const float* x0 = x + kbase;
    const float* x1 = x + xld + kbase;
    float a0 = 0.f, a1 = 0.f;
    for (int k = 0; k < klen; k++) {
        float wv = Wp[(long)k * N];
        a0 += x0[k] * wv;
        a1 += x1[k] * wv;
    }
    __shared__ float r0[4][64], r1[4][64];
    r0[g][t & 63] = a0; r1[g][t & 63] = a1;
    __syncthreads();
    if (t < 64) {
        a0 = r0[0][t] + r0[1][t] + r0[2][t] + r0[3][t];
        a1 = r1[0][t] + r1[1][t] + r1[2][t] + r1[3][t];
        long base = (long)(z * gridDim.y + kz) * 2 * N + (jb << 6) + t;
        part[base]     = a0;
        part[base + N] = a1;
    }
}

__global__ __launch_bounds__(256) void gemv_reduce(
    const float* __restrict__ part, const float* __restrict__ bias, long bzs,
    float* __restrict__ out, int N, int nz, int act)
{
    int idx = blockIdx.x * 256 + threadIdx.x;
    if (idx >= nz * 2 * N) return;
    int j  = idx % N;
    int bz = idx / N;
    int z  = bz >> 1;
    float s = bias[(long)z * bzs + j];
    const float* p = part + ((long)z * 8 * 2 + (bz & 1)) * N + j;
    #pragma unroll
    for (int kz = 0; kz < 8; kz++) s += p[(long)kz * 2 * N];
    if (act) s = fmaxf(s, 0.f);
    out[idx] = s;
}

// ---------- batched img K/V projections ----------
__global__ __launch_bounds__(256) void gemv_kv_part(
    const float* __restrict__ img,
    const float* __restrict__ Wuk, const float* __restrict__ Wuv,
    float* __restrict__ part)
{
    int jb = blockIdx.x, kz = blockIdx.y, z = blockIdx.z;
    int t = threadIdx.x;
    int j = (jb << 6) + (t & 63);
    int g = t >> 6;
    int kbase = (kz * 4 + g) * 64;
    const float* W = (z < 12) ? (Wuk + (long)z * 1048576) : (Wuv + (long)(z - 12) * 1048576);
    const float* Wp = W + (long)kbase * 1024 + j;
    const float* x0 = img + kbase;
    const float* x1 = img + 1024 + kbase;
    float a0 = 0.f, a1 = 0.f;
    for (int k = 0; k < 64; k++) {
        float wv = Wp[(long)k * 1024];
        a0 += x0[k] * wv;
        a1 += x1[k] * wv;
    }
    __shared__ float r0[4][64], r1[4][64];
    r0[g][t & 63] = a0; r1[g][t & 63] = a1;
    __syncthreads();
    if (t < 64) {
        a0 = r0[0][t] + r0[1][t] + r0[2][t] + r0[3][t];
        a1 = r1[0][t] + r1[1][t] + r1[2][t] + r1[3][t];
        long base = (long)(z * 4 + kz) * 2 * 1024 + (jb << 6) + t;
        part[base]        = a0;
        part[base + 1024] = a1;
    }
}

__global__ __launch_bounds__(256) void gemv_kv_reduce(
    const float* __restrict__ part,
    const float* __restrict__ buk, const float* __restrict__ buv,
    float* __restrict__ imgk, float* __restrict__ imgv)
{
    int idx = blockIdx.x * 256 + threadIdx.x;
    int z = idx >> 11;
    int bsel = (idx >> 10) & 1;
    int j = idx & 1023;
    float s = (z < 12) ? buk[z * 1024 + j] : buv[(z - 12) * 1024 + j];
    const float* p = part + ((long)z * 4 * 2 + bsel) * 1024 + j;
    #pragma unroll
    for (int kz = 0; kz < 4; kz++) s += p[(long)kz * 2 * 1024];
    if (z < 12) imgk[z * 2048 + bsel * 1024 + j] = s;
    else        imgv[(z - 12) * 2048 + bsel * 1024 + j] = s;
}

// ---------- LayerNorm (fallback path) ----------
__global__ __launch_bounds__(256) void ln_k(
    const float* __restrict__ in, __bf16* __restrict__ out,
    const float* __restrict__ g, const float* __restrict__ b)
{
    int row = blockIdx.x, t = threadIdx.x;
    float4 v = reinterpret_cast<const float4*>(in + (long)row * 1024)[t];
    float s1 = v.x + v.y + v.z + v.w;
    float s2 = v.x * v.x + v.y * v.y + v.z * v.z + v.w * v.w;
    #pragma unroll
    for (int o = 32; o >= 1; o >>= 1) { s1 += __shfl_xor(s1, o); s2 += __shfl_xor(s2, o); }
    __shared__ float r1[4], r2[4];
    int w = t >> 6;
    if ((t & 63) == 0) { r1[w] = s1; r2[w] = s2; }
    __syncthreads();
    s1 = r1[0] + r1[1] + r1[2] + r1[3];
    s2 = r2[0] + r2[1] + r2[2] + r2[3];
    float mean = s1 * (1.0f / 1024.0f);
    float var  = s2 * (1.0f / 1024.0f) - mean * mean;
    float rstd = rsqrtf(var + 1e-5f);
    float4 gg = reinterpret_cast<const float4*>(g)[t];
    float4 bb = reinterpret_cast<const float4*>(b)[t];
    bf16x4 o;
    o[0] = (__bf16)((v.x - mean) * rstd * gg.x + bb.x);
    o[1] = (__bf16)((v.y - mean) * rstd * gg.y + bb.y);
    o[2] = (__bf16)((v.z - mean) * rstd * gg.z + bb.z);
    o[3] = (__bf16)((v.w - mean) * rstd * gg.w + bb.w);
    *reinterpret_cast<bf16x4*>(out + (long)row * 1024 + t * 4) = o;
}

// ---------- fused: h += bias + sum(NP parts); out = LN(h) ----------
template<int NP>
__global__ __launch_bounds__(256) void lnadd_k(
    float* __restrict__ h, const float* __restrict__ part,
    const float* __restrict__ bias,
    const float* __restrict__ g, const float* __restrict__ b,
    __bf16* __restrict__ out)
{
    int row = blockIdx.x, t = threadIdx.x;
    long off = (long)row * 1024 + t * 4;
    float4 v = *reinterpret_cast<const float4*>(h + off);
    #pragma unroll
    for (int sp = 0; sp < NP; sp++) {
        float4 pv = *reinterpret_cast<const float4*>(part + sp * 1048576L + off);
        v.x += pv.x; v.y += pv.y; v.z += pv.z; v.w += pv.w;
    }
    float4 bi = reinterpret_cast<const float4*>(bias)[t];
    v.x += bi.x; v.y += bi.y; v.z += bi.z; v.w += bi.w;
    *reinterpret_cast<float4*>(h + off) = v;

    float s1 = v.x + v.y + v.z + v.w;
    float s2 = v.x * v.x + v.y * v.y + v.z * v.z + v.w * v.w;
    #pragma unroll
    for (int o = 32; o >= 1; o >>= 1) { s1 += __shfl_xor(s1, o); s2 += __shfl_xor(s2, o); }
    __shared__ float r1[4], r2[4];
    int w = t >> 6;
    if ((t & 63) == 0) { r1[w] = s1; r2[w] = s2; }
    __syncthreads();
    s1 = r1[0] + r1[1] + r1[2] + r1[3];
    s2 = r2[0] + r2[1] + r2[2] + r2[3];
    float mean = s1 * (1.0f / 1024.0f);
    float var  = s2 * (1.0f / 1024.0f) - mean * mean;
    float rstd = rsqrtf(var + 1e-5f);
    float4 gg = reinterpret_cast<const float4*>(g)[t];
    float4 bb = reinterpret_cast<const float4*>(b)[t];
    bf16x4 o;
    o[0] = (__bf16)((v.x - mean) * rstd * gg.x + bb.x);
    o[1] = (__bf16)((v.y - mean) * rstd * gg.y + bb.y);
    o[2] = (__bf16)((v.z - mean) * rstd * gg.z + bb.z);
    o[3] = (__bf16)((v.w - mean) * rstd * gg.w + bb.w);
    *reinterpret_cast<bf16x4*>(out + off) = o;
}

// ---------- LM head: 256x256, ledger schedule, min-LDS-read phases ----------
// Phase = (dbuf, kh): 12 ds_read_b128 (8 A-frag + 4 B-frag, each read ONCE) + 32 MFMA.
// Halves R10's LDS traffic (48->24 reads/wave/K-tile), which was the critical path.
__global__ __launch_bounds__(512, 2) void gemm_lm9(
    const __bf16* __restrict__ A, const __bf16* __restrict__ Bt,
    float* __restrict__ C, int N, int K, int GM, int GN)
{
    __shared__ __bf16 lds[65536];   // 128 KB: A 2db x 2half x 128x64 | B same at +32768
    const int total = GM * GN;
    const int q = total >> 3, r = total & 7;
    const int x = blockIdx.x & 7, jj = blockIdx.x >> 3;
    const int w0 = (x < r) ? x * (q + 1) + jj : r * (q + 1) + (x - r) * q + jj;
    const int m0 = (w0 % GM) * 256;
    const int n0 = (w0 / GM) * 256;

    const int t = threadIdx.x;
    const int wid = t >> 6, lane = t & 63;
    const int lo = lane & 15, hi = lane >> 4;
    const int wr = wid >> 2, wc = wid & 3;      // 2M x 4N waves; per-wave C = 128x64

    f32x4 acc[8][4] = {};

    const int srow = t >> 3;                    // 0..63
    const int skx  = (((t & 7) ^ (srow & 7)) << 3);
    const int sdst = t * 8;

#define A_OFF(db, hf) ((db) * 16384 + (hf) * 8192)
#define B_OFF(db, hf) (32768 + (db) * 16384 + (hf) * 8192)
#define STAGE_H(db, hsel, kt) do { \
    const int h_ = (hsel) & 1; \
    const __bf16* base_ = ((hsel) < 2) ? (A + (long)(m0 + h_ * 128) * K) \
                                       : (Bt + (long)(n0 + h_ * 128) * K); \
    const int d_ = ((hsel) < 2) ? A_OFF(db, h_) : B_OFF(db, h_); \
    GLDS16(base_ + (long)srow * K + (kt) * 64 + skx,        &lds[d_ + sdst]); \
    GLDS16(base_ + (long)(64 + srow) * K + (kt) * 64 + skx, &lds[d_ + 4096 + sdst]); \
} while (0)

    // phase: one kh of dbuf db; each fragment read once; 32 MFMA
#define PH(db, kh, DOSTAGE) do { \
    bf16x8 af_[8], bf_[4]; \
    _Pragma("unroll") \
    for (int mi = 0; mi < 8; mi++) \
        af_[mi] = *reinterpret_cast<const bf16x8*>( \
            &lds[A_OFF(db, wr) + fragoff(mi * 16 + lo, kh, hi)]); \
    _Pragma("unroll") \
    for (int ni = 0; ni < 4; ni++) \
        bf_[ni] = *reinterpret_cast<const bf16x8*>( \
            &lds[B_OFF(db, wc >> 1) + fragoff((wc & 1) * 64 + ni * 16 + lo, kh, hi)]); \
    DOSTAGE; \
    asm volatile("s_waitcnt lgkmcnt(0)" ::: "memory"); \
    SCHED_FENCE(); \
    __builtin_amdgcn_s_setprio(1); \
    _Pragma("unroll") \
    for (int mi = 0; mi < 8; mi++) \
        _Pragma("unroll") \
        for (int ni = 0; ni < 4; ni++) \
            acc[mi][ni] = __builtin_amdgcn_mfma_f32_16x16x32_bf16( \
                af_[mi], bf_[ni], acc[mi][ni], 0, 0, 0); \
    __builtin_amdgcn_s_setprio(0); \
} while (0)

    const int NKT = K >> 6;                     // 16
    STAGE_H(0, 0, 0); STAGE_H(0, 1, 0); STAGE_H(0, 2, 0); STAGE_H(0, 3, 0);

    for (int i = 0; i < NKT / 2; i++) {
        const int kt1 = 2 * i + 1, ktn = 2 * i + 2;
        // ---- compute D0 (kt=2i), stage kt1 -> D1 ----
        STAGE_H(1, 0, kt1);
        asm volatile("s_waitcnt vmcnt(2)" ::: "memory");   // D0's 8 loads landed
        SCHED_FENCE();
        __builtin_amdgcn_s_barrier();
        SCHED_FENCE();
        PH(0, 0, STAGE_H(1, 1, kt1); STAGE_H(1, 2, kt1));
        PH(0, 1, STAGE_H(1, 3, kt1));
        SCHED_FENCE();
        __builtin_amdgcn_s_barrier();
        SCHED_FENCE();
        // ---- compute D1 (kt=2i+1), stage ktn -> D0 ----
        if (ktn < NKT) {
            STAGE_H(0, 0, ktn);
            asm volatile("s_waitcnt vmcnt(2)" ::: "memory");
        } else {
            asm volatile("s_waitcnt vmcnt(0)" ::: "memory");
        }
        SCHED_FENCE();
        __builtin_amdgcn_s_barrier();
        SCHED_FENCE();
        PH(1, 0, if (ktn < NKT) { STAGE_H(0, 1, ktn); STAGE_H(0, 2, ktn); });
        PH(1, 1, if (ktn < NKT) STAGE_H(0, 3, ktn));
        SCHED_FENCE();
        __builtin_amdgcn_s_barrier();
        SCHED_FENCE();
    }
#undef PH
#undef STAGE_H
#undef A_OFF
#undef B_OFF

    #pragma unroll
    for (int mi = 0; mi < 8; mi++)
        #pragma unroll
        for (int ni = 0; ni < 4; ni++) {
            int col = n0 + wc * 64 + ni * 16 + lo;
            if (col < N) {
                #pragma unroll
                for (int rr = 0; rr < 4; rr++) {
                    int row = m0 + wr * 128 + mi * 16 + hi * 4 + rr;
                    C[(long)row * N + col] = acc[mi][ni][rr];
                }
            }
        }
}

// ---------- 64xBN GEMM, BK=64, swizzled, triple-buffered depth-2 prefetch ----------
template<int BN, int OUTBF16, int ACT, int PARTIAL>
__global__ __launch_bounds__(256) void gemm64(
    const __bf16* __restrict__ A, const __bf16* __restrict__ Bt,
    const float* __restrict__ bias, void* __restrict__ C,
    int N, int K, int GM, int GN, int NS)
{
    constexpr int NB = BN / 32;
    constexpr int LP = 2 + NB;
    const int total = GM * GN * NS;
    const int q = total >> 3, r = total & 7;
    const int x = blockIdx.x & 7, jj = blockIdx.x >> 3;
    const int w0 = (x < r) ? x * (q + 1) + jj : r * (q + 1) + (x - r) * q + jj;
    const int sp = w0 / (GM * GN);
    const int rem = w0 - sp * (GM * GN);
    const int m0 = (rem % GM) * 64;
    const int n0 = (rem / GM) * BN;

    __shared__ __bf16 As[3][64 * 64];
    __shared__ __bf16 Bs[3][BN * 64];
    const int t = threadIdx.x;
    const int wv = t >> 6, lane = t & 63;
    const int lo = lane & 15, hi = lane >> 4;
    const int wr = wv >> 1, wc = wv & 1;

    f32x4 acc[2][NB] = {};

    const int srow = t >> 3;
    const int skx  = (((t & 7) ^ (srow & 7)) << 3);
    const int sldst = t * 8;
    #define ST64(bf, kk) do { \
        _Pragma("unroll") \
        for (int i = 0; i < 2; i++) \
            GLDS16(A + (long)(m0 + i * 32 + srow) * K + (kk) + skx, &As[bf][i * 2048 + sldst]); \
        _Pragma("unroll") \
        for (int i = 0; i < NB; i++) \
            GLDS16(Bt + (long)(n0 + i * 32 + srow) * K + (kk) + skx, &Bs[bf][i * 2048 + sldst]); \
    } while (0)

    const int Ksp = K / NS;
    const int kbeg = sp * Ksp;
    const int T = Ksp >> 6;

    ST64(0, kbeg);
    if (T > 1) ST64(1, kbeg + 64);
    int bcur = 0;
    for (int it = 0; it < T; it++) {
        if (it + 2 < T) {
            int bst = bcur >= 1 ? bcur - 1 : bcur + 2;
            ST64(bst, kbeg + (it + 2) * 64);
            asm volatile("s_waitcnt vmcnt(%0)" :: "i"(2 * LP) : "memory");
        } else if (it + 1 < T) {
            asm volatile("s_waitcnt vmcnt(%0)" :: "i"(LP) : "memory");
        } else {
            asm volatile("s_waitcnt vmcnt(0)" ::: "memory");
        }
        SCHED_FENCE();
        __builtin_amdgcn_s_barrier();
        SCHED_FENCE();

        #pragma unroll
        for (int kh = 0; kh < 2; kh++) {
            bf16x8 afr[2], bfr[NB];
            #pragma unroll
            for (int mi = 0; mi < 2; mi++)
                afr[mi] = *reinterpret_cast<const bf16x8*>(&As[bcur][fragoff(wr * 32 + mi * 16 + lo, kh, hi)]);
            #pragma unroll
            for (int ni = 0; ni < NB; ni++)
                bfr[ni] = *reinterpret_cast<const bf16x8*>(&Bs[bcur][fragoff(wc * (BN / 2) + ni * 16 + lo, kh, hi)]);
            __builtin_amdgcn_s_setprio(1);
            #pragma unroll
            for (int mi = 0; mi < 2; mi++)
                #pragma unroll
                for (int ni = 0; ni < NB; ni++)
                    acc[mi][ni] = __builtin_amdgcn_mfma_f32_16x16x32_bf16(afr[mi], bfr[ni], acc[mi][ni], 0, 0, 0);
            __builtin_amdgcn_s_setprio(0);
        }

        SCHED_FENCE();
        __builtin_amdgcn_s_barrier();
        SCHED_FENCE();
        bcur = bcur < 2 ? bcur + 1 : 0;
    }
    #undef ST64

    const long coff = PARTIAL ? (long)sp * GM * 64 * N : 0;
    #pragma unroll
    for (int mi = 0; mi < 2; mi++)
        #pragma unroll
        for (int ni = 0; ni < NB; ni++) {
            int col = n0 + wc * (BN / 2) + ni * 16 + lo;
            float bv = (!PARTIAL && bias) ? bias[col] : 0.f;
            #pragma unroll
            for (int rr = 0; rr < 4; rr++) {
                int row = m0 + wr * 32 + mi * 16 + hi * 4 + rr;
                float v = acc[mi][ni][rr] + bv;
                if (ACT) v = gelu_f(v);
                if (OUTBF16) ((__bf16*)C)[(long)row * N + col] = (__bf16)v;
                else         ((float*)C)[coff + (long)row * N + col] = v;
            }
        }
}

// ---------- fallback 64x64 GEMM (BK=32) ----------
template<int OUTBF16, int ACT, int RES>
__global__ __launch_bounds__(256) void gemm_bb(
    const __bf16* __restrict__ A, const __bf16* __restrict__ Bt,
    const float* __restrict__ bias, const float* __restrict__ res,
    void* __restrict__ C, int N, int K)
{
    __shared__ __bf16 As[64 * 32];
    __shared__ __bf16 Bs[64 * 32];
    const int t = threadIdx.x;
    const int m0 = blockIdx.x * 64;
    const int n0 = blockIdx.y * 64;
    const int w = t >> 6, lane = t & 63;
    const int lo = lane & 15, hi = lane >> 4;
    const int wr = w >> 1, wc = w & 1;

    f32x4 acc[2][2] = {};

    for (int k0 = 0; k0 < K; k0 += 32) {
        __syncthreads();
        GLDS16(A  + (long)(m0 + (t >> 2)) * K + k0 + ((t & 3) << 3), &As[t * 8]);
        GLDS16(Bt + (long)(n0 + (t >> 2)) * K + k0 + ((t & 3) << 3), &Bs[t * 8]);
        __syncthreads();
        bf16x8 afr[2], bfr[2];
        #pragma unroll
        for (int mi = 0; mi < 2; mi++)
            afr[mi] = *reinterpret_cast<const bf16x8*>(&As[(wr * 32 + mi * 16 + lo) * 32 + hi * 8]);
        #pragma unroll
        for (int ni = 0; ni < 2; ni++)
            bfr[ni] = *reinterpret_cast<const bf16x8*>(&Bs[(wc * 32 + ni * 16 + lo) * 32 + hi * 8]);
        #pragma unroll
        for (int mi = 0; mi < 2; mi++)
            #pragma unroll
            for (int ni = 0; ni < 2; ni++)
                acc[mi][ni] = __builtin_amdgcn_mfma_f32_16x16x32_bf16(afr[mi], bfr[ni], acc[mi][ni], 0, 0, 0);
    }

    #pragma unroll
    for (int mi = 0; mi < 2; mi++)
        #pragma unroll
        for (int ni = 0; ni < 2; ni++) {
            int col = n0 + wc * 32 + ni * 16 + lo;
            float bv = bias ? bias[col] : 0.f;
            #pragma unroll
            for (int rr = 0; rr < 4; rr++) {
                int row = m0 + wr * 32 + mi * 16 + hi * 4 + rr;
                float v = acc[mi][ni][rr] + bv;
                if (ACT) v = gelu_f(v);
                if (RES) v += res[(long)row * N + col];
                if (OUTBF16) ((__bf16*)C)[(long)row * N + col] = (__bf16)v;
                else         ((float*)C)[(long)row * N + col] = v;
            }
        }
}

// ---------- LM head fallback: A bf16 (glds), Wt[N][K] fp32 reg-staged ----------
__global__ __launch_bounds__(256) void gemm_lm(
    const __bf16* __restrict__ A, const float* __restrict__ Wt,
    float* __restrict__ C, int N, int K)
{
    __shared__ __bf16 As[128 * 32];
    __shared__ __bf16 Bs[128 * 32];
    const int t = threadIdx.x;
    const int m0 = blockIdx.x * 128;
    const int n0 = blockIdx.y * 128;
    const int w = t >> 6, lane = t & 63;
    const int lo = lane & 15, hi = lane >> 4;
    const int wr = w >> 1, wc = w & 1;

    f32x4 acc[4][4] = {};

    for (int k0 = 0; k0 < K; k0 += 32) {
        __syncthreads();
        #pragma unroll
        for (int i = 0; i < 2; i++) {
            int c = i * 256 + t;
            GLDS16(A + (long)(m0 + (c >> 2)) * K + k0 + ((c & 3) << 3), &As[c * 8]);
        }
        #pragma unroll
        for (int i = 0; i < 2; i++) {
            int c = i * 256 + t;
            int nr = n0 + (c >> 2);
            bf16x8 bv;
            if (nr < N) {
                const float* wp = Wt + (long)nr * K + k0 + ((c & 3) << 3);
                float4 b0 = *reinterpret_cast<const float4*>(wp);
                float4 b1 = *reinterpret_cast<const float4*>(wp + 4);
                bv[0] = (__bf16)b0.x; bv[1] = (__bf16)b0.y; bv[2] = (__bf16)b0.z; bv[3] = (__bf16)b0.w;
                bv[4] = (__bf16)b1.x; bv[5] = (__bf16)b1.y; bv[6] = (__bf16)b1.z; bv[7] = (__bf16)b1.w;
            } else {
                #pragma unroll
                for (int qq = 0; qq < 8; qq++) bv[qq] = (__bf16)0.f;
            }
            *reinterpret_cast<bf16x8*>(&Bs[c * 8]) = bv;
        }
        __syncthreads();
        bf16x8 afr[4], bfr[4];
        #pragma unroll
        for (int mi = 0; mi < 4; mi++)
            afr[mi] = *reinterpret_cast<const bf16x8*>(&As[(wr * 64 + mi * 16 + lo) * 32 + hi * 8]);
        #pragma unroll
        for (int ni = 0; ni < 4; ni++)
            bfr[ni] = *reinterpret_cast<const bf16x8*>(&Bs[(wc * 64 + ni * 16 + lo) * 32 + hi * 8]);
        #pragma unroll
        for (int mi = 0; mi < 4; mi++)
            #pragma unroll
            for (int ni = 0; ni < 4; ni++)
                acc[mi][ni] = __builtin_amdgcn_mfma_f32_16x16x32_bf16(afr[mi], bfr[ni], acc[mi][ni], 0, 0, 0);
    }

    #pragma unroll
    for (int mi = 0; mi < 4; mi++)
        #pragma unroll
        for (int ni = 0; ni < 4; ni++) {
            int col = n0 + wc * 64 + ni * 16 + lo;
            if (col < N) {
                #pragma unroll
                for (int rr = 0; rr < 4; rr++) {
                    int row = m0 + wr * 64 + mi * 16 + hi * 4 + rr;
                    C[(long)row * N + col] = acc[mi][ni][rr];
                }
            }
        }
}

// ---------- merged: attention (blocks 0..255) + aux BW work (blocks >= 256) ----------
__global__ __launch_bounds__(256) void attn_aux(
    const __bf16* __restrict__ qkv,
    const float* __restrict__ imgk, const float* __restrict__ imgv,
    const float* __restrict__ amask, __bf16* __restrict__ out,
    int aux_mode,
    const float* __restrict__ Wa, const float* __restrict__ Wp,
    const float* __restrict__ Wf, const float* __restrict__ Wf2,
    __bf16* __restrict__ oa, __bf16* __restrict__ op,
    __bf16* __restrict__ of, __bf16* __restrict__ of2,
    const float* __restrict__ wte, __bf16* __restrict__ wteb, long nvalid)
{
    __shared__ __align__(16) char smem[28416];
    const int bid = blockIdx.x;
    if (bid >= 256) {
        if (aux_mode == 1)
            tcvt_body(bid - 256, Wa, Wp, Wf, Wf2, oa, op, of, of2, (float*)smem);
        else
            wcvt_body(bid - 256, wte, wteb, nvalid);
        return;
    }

    __bf16 (*Ks)[72] = (__bf16(*)[72])(smem);
    __bf16 (*Vt)[72] = (__bf16(*)[72])(smem + 9216);
    __bf16 (*Ps)[16][72] = (__bf16(*)[16][72])(smem + 18432);
    float* kimg_s = (float*)(smem + 27648);
    float* amv_s  = (float*)(smem + 27904);

    const int qb = bid & 7;
    const int h  = (bid >> 3) & 15;
    const int b  = bid >> 7;
    const int t = threadIdx.x, w = t >> 6, lane = t & 63;
    const int lo = lane & 15, hi = lane >> 4;

    const int kr8 = t >> 2, kd8 = (t & 3) * 16;
    const int vr8 = t & 63, vd8 = (t >> 6) * 16;

    const __bf16* qrow = qkv + (long)(b * 512 + qb * 64 + w * 16 + lo) * 3072 + h * 64;
    bf16x8 qf0 = *reinterpret_cast<const bf16x8*>(qrow + hi * 8);
    bf16x8 qf1 = *reinterpret_cast<const bf16x8*>(qrow + 32 + hi * 8);

    if (t < 64) kimg_s[t] = imgk[b * 1024 + h * 64 + t];
    __syncthreads();

    float simg = 0.f;
    #pragma unroll
    for (int i = 0; i < 8; i++)
        simg += (float)qf0[i] * kimg_s[hi * 8 + i] + (float)qf1[i] * kimg_s[32 + hi * 8 + i];
    simg += __shfl_xor(simg, 16);
    simg += __shfl_xor(simg, 32);
    simg *= 0.125f;

    float pimg[4], l_part[4];
    f32x4 o_acc[4];
    #pragma unroll
    for (int rr = 0; rr < 4; rr++) {
        pimg[rr] = __expf(__shfl(simg, hi * 4 + rr));
        l_part[rr] = 0.f;
    }
    #pragma unroll
    for (int df = 0; df < 4; df++) {
        float vi = imgv[b * 1024 + h * 64 + df * 16 + lo];
        #pragma unroll
        for (int rr = 0; rr < 4; rr++) o_acc[df][rr] = pimg[rr] * vi;
    }

    bf16x8 ck0, ck1, cv0, cv1;
    {
        const __bf16* ks = qkv + (long)(b * 512 + kr8) * 3072 + 1024 + h * 64 + kd8;
        ck0 = *reinterpret_cast<const bf16x8*>(ks);
        ck1 = *reinterpret_cast<const bf16x8*>(ks + 8);
        const __bf16* vs = qkv + (long)(b * 512 + vr8) * 3072 + 2048 + h * 64 + vd8;
        cv0 = *reinterpret_cast<const bf16x8*>(vs);
        cv1 = *reinterpret_cast<const bf16x8*>(vs + 8);
    }

    for (int kb = 0; kb <= qb; kb++) {
        bf16x8 nk0, nk1, nv0, nv1;
        const bool more = (kb < qb);
        if (more) {
            const __bf16* ks = qkv + (long)(b * 512 + (kb + 1) * 64 + kr8) * 3072 + 1024 + h * 64 + kd8;
            nk0 = *reinterpret_cast<const bf16x8*>(ks);
            nk1 = *reinterpret_cast<const bf16x8*>(ks + 8);
            const __bf16* vs = qkv + (long)(b * 512 + (kb + 1) * 64 + vr8) * 3072 + 2048 + h * 64 + vd8;
            nv0 = *reinterpret_cast<const bf16x8*>(vs);
            nv1 = *reinterpret_cast<const bf16x8*>(vs + 8);
        }
        __syncthreads();
        *reinterpret_cast<bf16x8*>(&Ks[kr8][kd8])     = ck0;
        *reinterpret_cast<bf16x8*>(&Ks[kr8][kd8 + 8]) = ck1;
        #pragma unroll
        for (int i = 0; i < 8; i++) { Vt[vd8 + i][vr8] = cv0[i]; Vt[vd8 + 8 + i][vr8] = cv1[i]; }
        if (t < 64) amv_s[t] = (1.0f - amask[b * 512 + kb * 64 + t]) * -10000.0f;
        __syncthreads();

        f32x4 sf[4];
        #pragma unroll
        for (int js = 0; js < 4; js++) {
            bf16x8 kf0 = *reinterpret_cast<const bf16x8*>(&Ks[js * 16 + lo][hi * 8]);
            bf16x8 kf1 = *reinterpret_cast<const bf16x8*>(&Ks[js * 16 + lo][32 + hi * 8]);
            f32x4 a = {};
            a = __builtin_amdgcn_mfma_f32_16x16x32_bf16(qf0, kf0, a, 0, 0, 0);
            a = __builtin_amdgcn_mfma_f32_16x16x32_bf16(qf1, kf1, a, 0, 0, 0);
            sf[js] = a;
        }
        #pragma unroll
        for (int js = 0; js < 4; js++) {
            float amv = amv_s[js * 16 + lo];
            #pragma unroll
            for (int rr = 0; rr < 4; rr++) {
                float sv = sf[js][rr] * 0.125f + amv;
                if (kb == qb) {
                    int qrw = w * 16 + hi * 4 + rr;
                    if (js * 16 + lo > qrw) sv = -10000.0f + amv;
                }
                float p = __expf(sv);
                l_part[rr] += p;
                Ps[w][hi * 4 + rr][js * 16 + lo] = (__bf16)p;
            }
        }
        #pragma unroll
        for (int jb = 0; jb < 2; jb++) {
            bf16x8 pf = *reinterpret_cast<const bf16x8*>(&Ps[w][lo][jb * 32 + hi * 8]);
            #pragma unroll
            for (int df = 0; df < 4; df++) {
                bf16x8 vf = *reinterpret_cast<const bf16x8*>(&Vt[df * 16 + lo][jb * 32 + hi * 8]);
                o_acc[df] = __builtin_amdgcn_mfma_f32_16x16x32_bf16(pf, vf, o_acc[df], 0, 0, 0);
            }
        }
        if (more) { ck0 = nk0; ck1 = nk1; cv0 = nv0; cv1 = nv1; }
    }

    float linv[4];
    #pragma unroll
    for (int rr = 0; rr < 4; rr++) {
        float ls = l_part[rr];
        #pragma unroll
        for (int off = 1; off < 16; off <<= 1) ls += __shfl_xor(ls, off);
        linv[rr] = 1.0f / (pimg[rr] + ls);
    }
    #pragma unroll
    for (int df = 0; df < 4; df++)
        #pragma unroll
        for (int rr = 0; rr < 4; rr++) {
            long row = b * 512 + qb * 64 + w * 16 + hi * 4 + rr;
            out[row * 1024 + h * 64 + df * 16 + lo] = (__bf16)(o_acc[df][rr] * linv[rr]);
        }
}

// ---------- host orchestration ----------
extern "C" void kernel_launch(void* const* d_in, const int* in_sizes, int n_in,
                              void* d_out, int out_size, void* d_ws, size_t ws_size,
                              hipStream_t stream) {
    (void)in_sizes; (void)n_in; (void)out_size;
    const int*   ids   = (const int*)d_in[0];
    const float* amask = (const float*)d_in[1];
    const float* ihs   = (const float*)d_in[2];
    const float* wte   = (const float*)d_in[3];
    const float* ftW1  = (const float*)d_in[4];
    const float* ftb1  = (const float*)d_in[5];
    const float* ftW2  = (const float*)d_in[6];
    const float* ftb2  = (const float*)d_in[7];
    const float* ln1g  = (const float*)d_in[8];
    const float* ln1b  = (const float*)d_in[9];
    const float* Wattn = (const float*)d_in[10];
    const float* battn = (const float*)d_in[11];
    const float* Wuk   = (const float*)d_in[12];
    const float* buk   = (const float*)d_in[13];
    const float* Wuv   = (const float*)d_in[14];
    const float* buv   = (const float*)d_in[15];
    const float* Wproj = (const float*)d_in[16];
    const float* bproj = (const float*)d_in[17];
    const float* ln2g  = (const float*)d_in[18];
    const float* ln2b  = (const float*)d_in[19];
    const float* Wfc   = (const float*)d_in[20];
    const float* bfc   = (const float*)d_in[21];
    const float* Wfc2  = (const float*)d_in[22];
    const float* bfc2  = (const float*)d_in[23];
    const float* lnfg  = (const float*)d_in[24];
    const float* lnfb  = (const float*)d_in[25];
    float* out = (float*)d_out;

    const long VP2 = 50432;              // V padded to multiple of 256
    const long NVALID = 50257L * 1024;
    char* base = (char*)d_ws;
    float* ftmp  = (float*)(base);
    float* img   = (float*)(base + (1 << 13));
    float* imgk  = (float*)(base + (1 << 14));
    float* imgv  = (float*)(base + 114688);
    float* part  = (float*)(base + 212992);
    float* h     = (float*)(base + 1048576);
    char* p = base + 5 * 1048576;
    __bf16* xb    = (__bf16*)p; p += 2 * 1048576;
    __bf16* qkvb  = (__bf16*)p; p += 6 * 1048576;
    __bf16* attob = (__bf16*)p; p += 2 * 1048576;
    __bf16* ffb   = (__bf16*)p; p += 8 * 1048576;
    __bf16* wtA0  = (__bf16*)p; p += 6 * 1048576;
    __bf16* wtP0  = (__bf16*)p; p += 2 * 1048576;
    __bf16* wtF0  = (__bf16*)p; p += 8 * 1048576;
    __bf16* wtF20 = (__bf16*)p; p += 8 * 1048576;
    __bf16* wteb  = (__bf16*)p; p += VP2 * 1024 * 2;
    size_t need1 = (size_t)(p - base);
    float* part_g = (float*)(base + need1);
    size_t need2 = need1 + 4 * 1048576 * sizeof(float);
    char* p2 = base + need2;
    __bf16* wtA1  = (__bf16*)p2; p2 += 6 * 1048576;
    __bf16* wtP1  = (__bf16*)p2; p2 += 2 * 1048576;
    __bf16* wtF1  = (__bf16*)p2; p2 += 8 * 1048576;
    __bf16* wtF21 = (__bf16*)p2; p2 += 8 * 1048576;
    size_t need3 = (size_t)(p2 - base);
    const bool big1 = (ws_size >= need1);
    const bool big2 = (ws_size >= need2);
    const bool big3 = (ws_size >= need3);

    __bf16* wtA_s[2]  = {wtA0, wtA1};
    __bf16* wtP_s[2]  = {wtP0, wtP1};
    __bf16* wtF_s[2]  = {wtF0, wtF1};
    __bf16* wtF2_s[2] = {wtF20, wtF21};

    dim3 b256(256);

    // pre-loop: union (embed+ln10 | tcvt layer0 | ft1 partial) then the serial gemv chain
    preloop0<<<dim3(4224), b256, 0, stream>>>(
        ids, wte, h, xb, ln1g, ln1b,
        Wattn, Wproj, Wfc, Wfc2, wtA0, wtP0, wtF0, wtF20,
        ihs, ftW1, part);
    gemv_reduce<<<dim3(8), b256, 0, stream>>>(part, ftb1, 0, ftmp, 1024, 1, 1);
    gemv_part<<<dim3(16, 8, 1), b256, 0, stream>>>(ftmp, 1024, ftW2, 0, part, 1024, 1024);
    gemv_reduce<<<dim3(8), b256, 0, stream>>>(part, ftb2, 0, img, 1024, 1, 0);
    gemv_kv_part<<<dim3(16, 4, 24), b256, 0, stream>>>(img, Wuk, Wuv, part);
    gemv_kv_reduce<<<dim3(192), b256, 0, stream>>>(part, buk, buv, imgk, imgv);

    for (int l = 0; l < 12; l++) {
        const int cs = big3 ? (l & 1) : 0;
        __bf16* cA  = wtA_s[cs];
        __bf16* cP  = wtP_s[cs];
        __bf16* cF  = wtF_s[cs];
        __bf16* cF2 = wtF2_s[cs];

        if (!big3 && l > 0) {
            tcvt_std<<<dim3(3072), b256, 0, stream>>>(
                Wattn + (long)l * 1024 * 3072, Wproj + (long)l * 1024 * 1024,
                Wfc + (long)l * 1024 * 4096, Wfc2 + (long)l * 4096 * 1024,
                wtA0, wtP0, wtF0, wtF20);
        }

        gemm64<128, 1, 0, 0><<<dim3(384), b256, 0, stream>>>(
            xb, cA, battn + l * 3072, qkvb, 3072, 1024, 16, 24, 1);

        if (big3 && l < 11) {
            const int ns = (l + 1) & 1;
            attn_aux<<<dim3(256 + 3072), b256, 0, stream>>>(
                qkvb, imgk + l * 2048, imgv + l * 2048, amask, attob, 1,
                Wattn + (long)(l + 1) * 1024 * 3072, Wproj + (long)(l + 1) * 1024 * 1024,
                Wfc + (long)(l + 1) * 1024 * 4096, Wfc2 + (long)(l + 1) * 4096 * 1024,
                wtA_s[ns], wtP_s[ns], wtF_s[ns], wtF2_s[ns],
                nullptr, nullptr, 0);
        } else if (big3 && l == 11) {
            attn_aux<<<dim3(256 + 6304), b256, 0, stream>>>(
                qkvb, imgk + l * 2048, imgv + l * 2048, amask, attob, 2,
                nullptr, nullptr, nullptr, nullptr,
                nullptr, nullptr, nullptr, nullptr,
                wte, wteb, NVALID);
        } else {
            attn_aux<<<dim3(256), b256, 0, stream>>>(
                qkvb, imgk + l * 2048, imgv + l * 2048, amask, attob, 0,
                nullptr, nullptr, nullptr, nullptr,
                nullptr, nullptr, nullptr, nullptr,
                nullptr, nullptr, 0);
        }

        const float* ng = (l < 11) ? (ln1g + (l + 1) * 1024) : lnfg;
        const float* nb = (l < 11) ? (ln1b + (l + 1) * 1024) : lnfb;
        if (big2) {
            gemm64<64, 0, 0, 1><<<dim3(512), b256, 0, stream>>>(
                attob, cP, nullptr, part_g, 1024, 1024, 16, 16, 2);
            lnadd_k<2><<<dim3(1024), b256, 0, stream>>>(
                h, part_g, bproj + l * 1024, ln2g + l * 1024, ln2b + l * 1024, xb);
            gemm64<128, 1, 1, 0><<<dim3(512), b256, 0, stream>>>(
                xb, cF, bfc + l * 4096, ffb, 4096, 1024, 16, 32, 1);
            gemm64<128, 0, 0, 1><<<dim3(512), b256, 0, stream>>>(
                ffb, cF2, nullptr, part_g, 1024, 4096, 16, 8, 4);
            lnadd_k<4><<<dim3(1024), b256, 0, stream>>>(
                h, part_g, bfc2 + l * 1024, ng, nb, xb);
        } else {
            gemm_bb<0, 0, 1><<<dim3(16, 16), b256, 0, stream>>>(
                attob, cP, bproj + l * 1024, h, h, 1024, 1024);
            ln_k<<<dim3(1024), b256, 0, stream>>>(h, xb, ln2g + l * 1024, ln2b + l * 1024);
            gemm64<128, 1, 1, 0><<<dim3(512), b256, 0, stream>>>(
                xb, cF, bfc + l * 4096, ffb, 4096, 1024, 16, 32, 1);
            gemm_bb<0, 0, 1><<<dim3(16, 16), b256, 0, stream>>>(
                ffb, cF2, bfc2 + l * 1024, h, h, 1024, 4096);
            ln_k<<<dim3(1024), b256, 0, stream>>>(h, xb, ng, nb);
        }
    }

    // xb holds lnf(h)
    if (big1) {
        if (!big3)
            wcvt_std<<<dim3((unsigned)(VP2 * 1024 / 8192)), b256, 0, stream>>>(wte, wteb, NVALID);
        gemm_lm9<<<dim3(4 * (int)(VP2 / 256)), dim3(512), 0, stream>>>(
            xb, wteb, out, 50257, 1024, 4, (int)(VP2 / 256));
    } else {
        gemm_lm<<<dim3(8, 393), b256, 0, stream>>>(xb, wte, out, 50257, 1024);
    }
}

// Round 13
// 1429.526 us; speedup vs baseline: 1.0851x; 1.0851x over previous
//
#include <hip/hip_runtime.h>
#include <cstdint>

// B=2, S=512, D=1024, H=16, HD=64, L=12, V=50257, DFF=4096

typedef __bf16 bf16x8 __attribute__((ext_vector_type(8)));
typedef __bf16 bf16x4 __attribute__((ext_vector_type(4)));
typedef float  f32x4  __attribute__((ext_vector_type(4)));

#define GLDS16(g, l) __builtin_amdgcn_global_load_lds( \
    (const __attribute__((address_space(1))) unsigned int*)(g), \
    (__attribute__((address_space(3))) unsigned int*)(l), 16, 0, 0)

#define SCHED_FENCE() __builtin_amdgcn_sched_barrier(0)

__device__ __forceinline__ float gelu_f(float x) {
    float u = 1.5957691216057308f * (x + 0.044715f * x * x * x);
    float e = __expf(u);
    float t = 1.0f - 2.0f / (e + 1.0f);
    return 0.5f * x * (1.0f + t);
}

// swizzled fragment offset in a [rows][64] bf16 LDS tile (T2 XOR, pairs with staging perm)
__device__ __forceinline__ int fragoff(int row, int kh, int hi) {
    return row * 64 + ((kh * 32 + hi * 8) ^ ((row & 7) << 3));
}

// ---------- weight transpose+convert body: 64x64 f32 tile -> bf16 [N][K] ----------
__device__ __forceinline__ void tcvt_body(
    int id, const float* __restrict__ Wa, const float* __restrict__ Wp,
    const float* __restrict__ Wf, const float* __restrict__ Wf2,
    __bf16* __restrict__ oa, __bf16* __restrict__ op,
    __bf16* __restrict__ of, __bf16* __restrict__ of2, float* tile)
{
    const float* src; __bf16* dst; int K, N, kb, nb;
    if (id < 768)       { src = Wa;  dst = oa;  K = 1024; N = 3072; kb = id & 15; nb = id >> 4; }
    else if (id < 1024) { id -= 768;  src = Wp;  dst = op;  K = 1024; N = 1024; kb = id & 15; nb = id >> 4; }
    else if (id < 2048) { id -= 1024; src = Wf;  dst = of;  K = 1024; N = 4096; kb = id & 15; nb = id >> 4; }
    else                { id -= 2048; src = Wf2; dst = of2; K = 4096; N = 1024; kb = id & 63; nb = id >> 6; }
    const int k0 = kb * 64, n0 = nb * 64;
    const int t = threadIdx.x;
    #pragma unroll
    for (int i = 0; i < 4; i++) {
        int r = i * 16 + (t >> 4), c = (t & 15) * 4;
        float4 v = *reinterpret_cast<const float4*>(src + (long)(k0 + r) * N + n0 + c);
        tile[r * 65 + c] = v.x; tile[r * 65 + c + 1] = v.y;
        tile[r * 65 + c + 2] = v.z; tile[r * 65 + c + 3] = v.w;
    }
    __syncthreads();
    const int nrow = t >> 2, kc = (t & 3) * 16;
    bf16x8 o0, o1;
    #pragma unroll
    for (int i = 0; i < 8; i++) {
        o0[i] = (__bf16)tile[(kc + i) * 65 + nrow];
        o1[i] = (__bf16)tile[(kc + 8 + i) * 65 + nrow];
    }
    *reinterpret_cast<bf16x8*>(dst + (long)(n0 + nrow) * K + k0 + kc)     = o0;
    *reinterpret_cast<bf16x8*>(dst + (long)(n0 + nrow) * K + k0 + kc + 8) = o1;
}

// ---------- wte fp32 -> bf16 body ----------
__device__ __forceinline__ void wcvt_body(
    int id, const float* __restrict__ wte, __bf16* __restrict__ out, long nvalid)
{
    long base = (long)id * 8192 + threadIdx.x * 8;
    #pragma unroll
    for (int i = 0; i < 4; i++) {
        long e = base + (long)i * 2048;
        bf16x8 o;
        if (e < nvalid) {
            float4 a = *reinterpret_cast<const float4*>(wte + e);
            float4 b = *reinterpret_cast<const float4*>(wte + e + 4);
            o[0] = (__bf16)a.x; o[1] = (__bf16)a.y; o[2] = (__bf16)a.z; o[3] = (__bf16)a.w;
            o[4] = (__bf16)b.x; o[5] = (__bf16)b.y; o[6] = (__bf16)b.z; o[7] = (__bf16)b.w;
        } else {
            #pragma unroll
            for (int q = 0; q < 8; q++) o[q] = (__bf16)0.f;
        }
        *reinterpret_cast<bf16x8*>(out + e) = o;
    }
}

// ---------- embedding + layer-0 LN body ----------
__device__ __forceinline__ void embed_body(
    int row, const int* __restrict__ ids, const float* __restrict__ wte,
    float* __restrict__ h, __bf16* __restrict__ xb,
    const float* __restrict__ g, const float* __restrict__ b, float* red)
{
    int s = row & 511;
    int t = threadIdx.x;
    long id = ids[row];
    float4 v1 = reinterpret_cast<const float4*>(wte + id * 1024)[t];
    float4 v2 = reinterpret_cast<const float4*>(wte + (long)s * 1024)[t];
    float4 v; v.x = v1.x + v2.x; v.y = v1.y + v2.y; v.z = v1.z + v2.z; v.w = v1.w + v2.w;
    reinterpret_cast<float4*>(h + (long)row * 1024)[t] = v;

    float s1 = v.x + v.y + v.z + v.w;
    float s2 = v.x * v.x + v.y * v.y + v.z * v.z + v.w * v.w;
    #pragma unroll
    for (int o = 32; o >= 1; o >>= 1) { s1 += __shfl_xor(s1, o); s2 += __shfl_xor(s2, o); }
    int w = t >> 6;
    if ((t & 63) == 0) { red[w] = s1; red[4 + w] = s2; }
    __syncthreads();
    s1 = red[0] + red[1] + red[2] + red[3];
    s2 = red[4] + red[5] + red[6] + red[7];
    float mean = s1 * (1.0f / 1024.0f);
    float var  = s2 * (1.0f / 1024.0f) - mean * mean;
    float rstd = rsqrtf(var + 1e-5f);
    float4 gg = reinterpret_cast<const float4*>(g)[t];
    float4 bb = reinterpret_cast<const float4*>(b)[t];
    bf16x4 o;
    o[0] = (__bf16)((v.x - mean) * rstd * gg.x + bb.x);
    o[1] = (__bf16)((v.y - mean) * rstd * gg.y + bb.y);
    o[2] = (__bf16)((v.z - mean) * rstd * gg.z + bb.z);
    o[3] = (__bf16)((v.w - mean) * rstd * gg.w + bb.w);
    *reinterpret_cast<bf16x4*>(xb + (long)row * 1024 + t * 4) = o;
}

// ---------- ft first-layer gemv partial body (z=0, K=N=1024, ksplit-8) ----------
__device__ __forceinline__ void ftpart_body(
    int id, const float* __restrict__ x, const float* __restrict__ W,
    float* __restrict__ part, float* red)
{
    int jb = id & 15, kz = id >> 4;
    int t = threadIdx.x;
    int j = (jb << 6) + (t & 63);
    int g = t >> 6;
    int kbase = (kz * 4 + g) * 32;
    const float* Wp = W + (long)kbase * 1024 + j;
    const float* x0 = x + kbase;
    const float* x1 = x + 1024 + kbase;
    float a0 = 0.f, a1 = 0.f;
    for (int k = 0; k < 32; k++) {
        float wv = Wp[(long)k * 1024];
        a0 += x0[k] * wv;
        a1 += x1[k] * wv;
    }
    red[g * 64 + (t & 63)] = a0;
    red[256 + g * 64 + (t & 63)] = a1;
    __syncthreads();
    if (t < 64) {
        a0 = red[t] + red[64 + t] + red[128 + t] + red[192 + t];
        a1 = red[256 + t] + red[320 + t] + red[384 + t] + red[448 + t];
        long base = (long)kz * 2 * 1024 + (jb << 6) + t;
        part[base]        = a0;
        part[base + 1024] = a1;
    }
}

// ---------- pre-loop union: embed (0..1023) | tcvt layer0 (1024..4095) | ft1 part ----------
__global__ __launch_bounds__(256) void preloop0(
    const int* __restrict__ ids, const float* __restrict__ wte,
    float* __restrict__ h, __bf16* __restrict__ xb,
    const float* __restrict__ g, const float* __restrict__ b,
    const float* __restrict__ Wa, const float* __restrict__ Wp,
    const float* __restrict__ Wf, const float* __restrict__ Wf2,
    __bf16* __restrict__ oa, __bf16* __restrict__ op,
    __bf16* __restrict__ of, __bf16* __restrict__ of2,
    const float* __restrict__ ihs, const float* __restrict__ ftW1,
    float* __restrict__ part)
{
    __shared__ __align__(16) char smem[16640];
    const int bid = blockIdx.x;
    if (bid < 1024)       embed_body(bid, ids, wte, h, xb, g, b, (float*)smem);
    else if (bid < 4096)  tcvt_body(bid - 1024, Wa, Wp, Wf, Wf2, oa, op, of, of2, (float*)smem);
    else                  ftpart_body(bid - 4096, ihs, ftW1, part, (float*)smem);
}

__global__ __launch_bounds__(256) void tcvt_std(
    const float* __restrict__ Wa, const float* __restrict__ Wp,
    const float* __restrict__ Wf, const float* __restrict__ Wf2,
    __bf16* __restrict__ oa, __bf16* __restrict__ op,
    __bf16* __restrict__ of, __bf16* __restrict__ of2)
{
    __shared__ float tile[64 * 65];
    tcvt_body(blockIdx.x, Wa, Wp, Wf, Wf2, oa, op, of, of2, tile);
}

__global__ __launch_bounds__(256) void wcvt_std(
    const float* __restrict__ wte, __bf16* __restrict__ out, long nvalid)
{
    wcvt_body(blockIdx.x, wte, out, nvalid);
}

// ---------- small GEMV path (img feature transform), ksplit-8 ----------
__global__ __launch_bounds__(256) void gemv_part(
    const float* __restrict__ x, int xld,
    const float* __restrict__ W, long wzs,
    float* __restrict__ part, int K, int N)
{
    int jb = blockIdx.x, kz = blockIdx.y, z = blockIdx.z;
    int t = threadIdx.x;
    int j = (jb << 6) + (t & 63);
    int g = t >> 6;
    int klen = K / (gridDim.y * 4);
    int kbase = (kz * 4 + g) * klen;
    const float* Wp = W + (long)z * wzs + (long)kbase * N + j;
    const float* x0 = x + kbase;
    const float* x1 = x + xld + kbase;
    float a0 = 0.f, a1 = 0.f;
    for (int k = 0; k < klen; k++) {
        float wv = Wp[(long)k * N];
        a0 += x0[k] * wv;
        a1 += x1[k] * wv;
    }
    __shared__ float r0[4][64], r1[4][64];
    r0[g][t & 63] = a0; r1[g][t & 63] = a1;
    __syncthreads();
    if (t < 64) {
        a0 = r0[0][t] + r0[1][t] + r0[2][t] + r0[3][t];
        a1 = r1[0][t] + r1[1][t] + r1[2][t] + r1[3][t];
        long base = (long)(z * gridDim.y + kz) * 2 * N + (jb << 6) + t;
        part[base]     = a0;
        part[base + N] = a1;
    }
}

__global__ __launch_bounds__(256) void gemv_reduce(
    const float* __restrict__ part, const float* __restrict__ bias, long bzs,
    float* __restrict__ out, int N, int nz, int act)
{
    int idx = blockIdx.x * 256 + threadIdx.x;
    if (idx >= nz * 2 * N) return;
    int j  = idx % N;
    int bz = idx / N;
    int z  = bz >> 1;
    float s = bias[(long)z * bzs + j];
    const float* p = part + ((long)z * 8 * 2 + (bz & 1)) * N + j;
    #pragma unroll
    for (int kz = 0; kz < 8; kz++) s += p[(long)kz * 2 * N];
    if (act) s = fmaxf(s, 0.f);
    out[idx] = s;
}

// ---------- batched img K/V projections ----------
__global__ __launch_bounds__(256) void gemv_kv_part(
    const float* __restrict__ img,
    const float* __restrict__ Wuk, const float* __restrict__ Wuv,
    float* __restrict__ part)
{
    int jb = blockIdx.x, kz = blockIdx.y, z = blockIdx.z;
    int t = threadIdx.x;
    int j = (jb << 6) + (t & 63);
    int g = t >> 6;
    int kbase = (kz * 4 + g) * 64;
    const float* W = (z < 12) ? (Wuk + (long)z * 1048576) : (Wuv + (long)(z - 12) * 1048576);
    const float* Wp = W + (long)kbase * 1024 + j;
    const float* x0 = img + kbase;
    const float* x1 = img + 1024 + kbase;
    float a0 = 0.f, a1 = 0.f;
    for (int k = 0; k < 64; k++) {
        float wv = Wp[(long)k * 1024];
        a0 += x0[k] * wv;
        a1 += x1[k] * wv;
    }
    __shared__ float r0[4][64], r1[4][64];
    r0[g][t & 63] = a0; r1[g][t & 63] = a1;
    __syncthreads();
    if (t < 64) {
        a0 = r0[0][t] + r0[1][t] + r0[2][t] + r0[3][t];
        a1 = r1[0][t] + r1[1][t] + r1[2][t] + r1[3][t];
        long base = (long)(z * 4 + kz) * 2 * 1024 + (jb << 6) + t;
        part[base]        = a0;
        part[base + 1024] = a1;
    }
}

__global__ __launch_bounds__(256) void gemv_kv_reduce(
    const float* __restrict__ part,
    const float* __restrict__ buk, const float* __restrict__ buv,
    float* __restrict__ imgk, float* __restrict__ imgv)
{
    int idx = blockIdx.x * 256 + threadIdx.x;
    int z = idx >> 11;
    int bsel = (idx >> 10) & 1;
    int j = idx & 1023;
    float s = (z < 12) ? buk[z * 1024 + j] : buv[(z - 12) * 1024 + j];
    const float* p = part + ((long)z * 4 * 2 + bsel) * 1024 + j;
    #pragma unroll
    for (int kz = 0; kz < 4; kz++) s += p[(long)kz * 2 * 1024];
    if (z < 12) imgk[z * 2048 + bsel * 1024 + j] = s;
    else        imgv[(z - 12) * 2048 + bsel * 1024 + j] = s;
}

// ---------- LayerNorm (fallback path) ----------
__global__ __launch_bounds__(256) void ln_k(
    const float* __restrict__ in, __bf16* __restrict__ out,
    const float* __restrict__ g, const float* __restrict__ b)
{
    int row = blockIdx.x, t = threadIdx.x;
    float4 v = reinterpret_cast<const float4*>(in + (long)row * 1024)[t];
    float s1 = v.x + v.y + v.z + v.w;
    float s2 = v.x * v.x + v.y * v.y + v.z * v.z + v.w * v.w;
    #pragma unroll
    for (int o = 32; o >= 1; o >>= 1) { s1 += __shfl_xor(s1, o); s2 += __shfl_xor(s2, o); }
    __shared__ float r1[4], r2[4];
    int w = t >> 6;
    if ((t & 63) == 0) { r1[w] = s1; r2[w] = s2; }
    __syncthreads();
    s1 = r1[0] + r1[1] + r1[2] + r1[3];
    s2 = r2[0] + r2[1] + r2[2] + r2[3];
    float mean = s1 * (1.0f / 1024.0f);
    float var  = s2 * (1.0f / 1024.0f) - mean * mean;
    float rstd = rsqrtf(var + 1e-5f);
    float4 gg = reinterpret_cast<const float4*>(g)[t];
    float4 bb = reinterpret_cast<const float4*>(b)[t];
    bf16x4 o;
    o[0] = (__bf16)((v.x - mean) * rstd * gg.x + bb.x);
    o[1] = (__bf16)((v.y - mean) * rstd * gg.y + bb.y);
    o[2] = (__bf16)((v.z - mean) * rstd * gg.z + bb.z);
    o[3] = (__bf16)((v.w - mean) * rstd * gg.w + bb.w);
    *reinterpret_cast<bf16x4*>(out + (long)row * 1024 + t * 4) = o;
}

// ---------- fused: h += bias + sum(NP parts); out = LN(h) ----------
template<int NP>
__global__ __launch_bounds__(256) void lnadd_k(
    float* __restrict__ h, const float* __restrict__ part,
    const float* __restrict__ bias,
    const float* __restrict__ g, const float* __restrict__ b,
    __bf16* __restrict__ out)
{
    int row = blockIdx.x, t = threadIdx.x;
    long off = (long)row * 1024 + t * 4;
    float4 v = *reinterpret_cast<const float4*>(h + off);
    #pragma unroll
    for (int sp = 0; sp < NP; sp++) {
        float4 pv = *reinterpret_cast<const float4*>(part + sp * 1048576L + off);
        v.x += pv.x; v.y += pv.y; v.z += pv.z; v.w += pv.w;
    }
    float4 bi = reinterpret_cast<const float4*>(bias)[t];
    v.x += bi.x; v.y += bi.y; v.z += bi.z; v.w += bi.w;
    *reinterpret_cast<float4*>(h + off) = v;

    float s1 = v.x + v.y + v.z + v.w;
    float s2 = v.x * v.x + v.y * v.y + v.z * v.z + v.w * v.w;
    #pragma unroll
    for (int o = 32; o >= 1; o >>= 1) { s1 += __shfl_xor(s1, o); s2 += __shfl_xor(s2, o); }
    __shared__ float r1[4], r2[4];
    int w = t >> 6;
    if ((t & 63) == 0) { r1[w] = s1; r2[w] = s2; }
    __syncthreads();
    s1 = r1[0] + r1[1] + r1[2] + r1[3];
    s2 = r2[0] + r2[1] + r2[2] + r2[3];
    float mean = s1 * (1.0f / 1024.0f);
    float var  = s2 * (1.0f / 1024.0f) - mean * mean;
    float rstd = rsqrtf(var + 1e-5f);
    float4 gg = reinterpret_cast<const float4*>(g)[t];
    float4 bb = reinterpret_cast<const float4*>(b)[t];
    bf16x4 o;
    o[0] = (__bf16)((v.x - mean) * rstd * gg.x + bb.x);
    o[1] = (__bf16)((v.y - mean) * rstd * gg.y + bb.y);
    o[2] = (__bf16)((v.z - mean) * rstd * gg.z + bb.z);
    o[3] = (__bf16)((v.w - mean) * rstd * gg.w + bb.w);
    *reinterpret_cast<bf16x4*>(out + off) = o;
}

// ---------- LM head: 256x256 8-phase schedule (R10's proven gemm_lm8), 128 KB LDS ----------
__global__ __launch_bounds__(512, 2) void gemm_lm8(
    const __bf16* __restrict__ A, const __bf16* __restrict__ Bt,
    float* __restrict__ C, int N, int K, int GM, int GN)
{
    __shared__ __bf16 lds[65536];   // 128 KB: A 2db x 2half x 128x64 | B same at +32768
    const int total = GM * GN;
    const int q = total >> 3, r = total & 7;
    const int x = blockIdx.x & 7, jj = blockIdx.x >> 3;
    const int w0 = (x < r) ? x * (q + 1) + jj : r * (q + 1) + (x - r) * q + jj;
    const int m0 = (w0 % GM) * 256;
    const int n0 = (w0 / GM) * 256;

    const int t = threadIdx.x;
    const int wid = t >> 6, lane = t & 63;
    const int lo = lane & 15, hi = lane >> 4;
    const int wr = wid >> 2, wc = wid & 3;      // 2M x 4N waves; per-wave C = 128x64

    f32x4 acc[8][4] = {};

    const int srow = t >> 3;                    // 0..63
    const int skx  = (((t & 7) ^ (srow & 7)) << 3);
    const int sdst = t * 8;

#define A_OFF(db, hf) ((db) * 16384 + (hf) * 8192)
#define B_OFF(db, hf) (32768 + (db) * 16384 + (hf) * 8192)
#define STAGE_H(db, hsel, kt) do { \
    const int h_ = (hsel) & 1; \
    const __bf16* base_ = ((hsel) < 2) ? (A + (long)(m0 + h_ * 128) * K) \
                                       : (Bt + (long)(n0 + h_ * 128) * K); \
    const int d_ = ((hsel) < 2) ? A_OFF(db, h_) : B_OFF(db, h_); \
    GLDS16(base_ + (long)srow * K + (kt) * 64 + skx,        &lds[d_ + sdst]); \
    GLDS16(base_ + (long)(64 + srow) * K + (kt) * 64 + skx, &lds[d_ + 4096 + sdst]); \
} while (0)

    // one phase: quadrant (m,n) of dbuf db; 12 ds_read_b128 + 16 MFMA
#define PH(db, m, n, DOSTAGE) do { \
    bf16x8 af_[4][2], bf_[2][2]; \
    _Pragma("unroll") \
    for (int mi = 0; mi < 4; mi++) \
        _Pragma("unroll") \
        for (int kh = 0; kh < 2; kh++) \
            af_[mi][kh] = *reinterpret_cast<const bf16x8*>( \
                &lds[A_OFF(db, wr) + fragoff(((m) * 4 + mi) * 16 + lo, kh, hi)]); \
    _Pragma("unroll") \
    for (int ni = 0; ni < 2; ni++) \
        _Pragma("unroll") \
        for (int kh = 0; kh < 2; kh++) \
            bf_[ni][kh] = *reinterpret_cast<const bf16x8*>( \
                &lds[B_OFF(db, wc >> 1) + fragoff((wc & 1) * 64 + ((n) * 2 + ni) * 16 + lo, kh, hi)]); \
    DOSTAGE; \
    asm volatile("s_waitcnt lgkmcnt(0)" ::: "memory"); \
    SCHED_FENCE(); \
    __builtin_amdgcn_s_setprio(1); \
    _Pragma("unroll") \
    for (int mi = 0; mi < 4; mi++) \
        _Pragma("unroll") \
        for (int ni = 0; ni < 2; ni++) \
            _Pragma("unroll") \
            for (int kh = 0; kh < 2; kh++) \
                acc[(m) * 4 + mi][(n) * 2 + ni] = __builtin_amdgcn_mfma_f32_16x16x32_bf16( \
                    af_[mi][kh], bf_[ni][kh], acc[(m) * 4 + mi][(n) * 2 + ni], 0, 0, 0); \
    __builtin_amdgcn_s_setprio(0); \
} while (0)

    const int NKT = K >> 6;                     // 16 K-tiles of 64
    STAGE_H(0, 0, 0); STAGE_H(0, 1, 0); STAGE_H(0, 2, 0); STAGE_H(0, 3, 0);

    for (int i = 0; i < NKT / 2; i++) {
        const int kt1 = 2 * i + 1, ktn = 2 * i + 2;
        // ---- group A: compute D0 (kt=2i), stage kt1 -> D1 ----
        STAGE_H(1, 0, kt1);
        asm volatile("s_waitcnt vmcnt(2)" ::: "memory");   // D0's 8 loads landed
        SCHED_FENCE();
        __builtin_amdgcn_s_barrier();
        SCHED_FENCE();
        PH(0, 0, 0, (void)0);
        PH(0, 0, 1, STAGE_H(1, 1, kt1));
        PH(0, 1, 0, STAGE_H(1, 2, kt1));
        PH(0, 1, 1, STAGE_H(1, 3, kt1));
        SCHED_FENCE();
        __builtin_amdgcn_s_barrier();                      // all D0 reads done
        SCHED_FENCE();
        // ---- group B: compute D1 (kt=2i+1), stage ktn -> D0 ----
        if (ktn < NKT) {
            STAGE_H(0, 0, ktn);
            asm volatile("s_waitcnt vmcnt(2)" ::: "memory");
        } else {
            asm volatile("s_waitcnt vmcnt(0)" ::: "memory");
        }
        SCHED_FENCE();
        __builtin_amdgcn_s_barrier();                      // D1's 8 loads landed
        SCHED_FENCE();
        PH(1, 0, 0, (void)0);
        PH(1, 0, 1, if (ktn < NKT) STAGE_H(0, 1, ktn));
        PH(1, 1, 0, if (ktn < NKT) STAGE_H(0, 2, ktn));
        PH(1, 1, 1, if (ktn < NKT) STAGE_H(0, 3, ktn));
        SCHED_FENCE();
        __builtin_amdgcn_s_barrier();                      // all D1 reads done
        SCHED_FENCE();
    }
#undef PH
#undef STAGE_H
#undef A_OFF
#undef B_OFF

    #pragma unroll
    for (int mi = 0; mi < 8; mi++)
        #pragma unroll
        for (int ni = 0; ni < 4; ni++) {
            int col = n0 + wc * 64 + ni * 16 + lo;
            if (col < N) {
                #pragma unroll
                for (int rr = 0; rr < 4; rr++) {
                    int row = m0 + wr * 128 + mi * 16 + hi * 4 + rr;
                    C[(long)row * N + col] = acc[mi][ni][rr];
                }
            }
        }
}

// ---------- 64xBN GEMM, BK=64, swizzled, triple-buffered depth-2 prefetch ----------
template<int BN, int OUTBF16, int ACT, int PARTIAL>
__global__ __launch_bounds__(256) void gemm64(
    const __bf16* __restrict__ A, const __bf16* __restrict__ Bt,
    const float* __restrict__ bias, void* __restrict__ C,
    int N, int K, int GM, int GN, int NS)
{
    constexpr int NB = BN / 32;
    constexpr int LP = 2 + NB;
    const int total = GM * GN * NS;
    const int q = total >> 3, r = total & 7;
    const int x = blockIdx.x & 7, jj = blockIdx.x >> 3;
    const int w0 = (x < r) ? x * (q + 1) + jj : r * (q + 1) + (x - r) * q + jj;
    const int sp = w0 / (GM * GN);
    const int rem = w0 - sp * (GM * GN);
    const int m0 = (rem % GM) * 64;
    const int n0 = (rem / GM) * BN;

    __shared__ __bf16 As[3][64 * 64];
    __shared__ __bf16 Bs[3][BN * 64];
    const int t = threadIdx.x;
    const int wv = t >> 6, lane = t & 63;
    const int lo = lane & 15, hi = lane >> 4;
    const int wr = wv >> 1, wc = wv & 1;

    f32x4 acc[2][NB] = {};

    const int srow = t >> 3;
    const int skx  = (((t & 7) ^ (srow & 7)) << 3);
    const int sldst = t * 8;
    #define ST64(bf, kk) do { \
        _Pragma("unroll") \
        for (int i = 0; i < 2; i++) \
            GLDS16(A + (long)(m0 + i * 32 + srow) * K + (kk) + skx, &As[bf][i * 2048 + sldst]); \
        _Pragma("unroll") \
        for (int i = 0; i < NB; i++) \
            GLDS16(Bt + (long)(n0 + i * 32 + srow) * K + (kk) + skx, &Bs[bf][i * 2048 + sldst]); \
    } while (0)

    const int Ksp = K / NS;
    const int kbeg = sp * Ksp;
    const int T = Ksp >> 6;

    ST64(0, kbeg);
    if (T > 1) ST64(1, kbeg + 64);
    int bcur = 0;
    for (int it = 0; it < T; it++) {
        if (it + 2 < T) {
            int bst = bcur >= 1 ? bcur - 1 : bcur + 2;
            ST64(bst, kbeg + (it + 2) * 64);
            asm volatile("s_waitcnt vmcnt(%0)" :: "i"(2 * LP) : "memory");
        } else if (it + 1 < T) {
            asm volatile("s_waitcnt vmcnt(%0)" :: "i"(LP) : "memory");
        } else {
            asm volatile("s_waitcnt vmcnt(0)" ::: "memory");
        }
        SCHED_FENCE();
        __builtin_amdgcn_s_barrier();
        SCHED_FENCE();

        #pragma unroll
        for (int kh = 0; kh < 2; kh++) {
            bf16x8 afr[2], bfr[NB];
            #pragma unroll
            for (int mi = 0; mi < 2; mi++)
                afr[mi] = *reinterpret_cast<const bf16x8*>(&As[bcur][fragoff(wr * 32 + mi * 16 + lo, kh, hi)]);
            #pragma unroll
            for (int ni = 0; ni < NB; ni++)
                bfr[ni] = *reinterpret_cast<const bf16x8*>(&Bs[bcur][fragoff(wc * (BN / 2) + ni * 16 + lo, kh, hi)]);
            __builtin_amdgcn_s_setprio(1);
            #pragma unroll
            for (int mi = 0; mi < 2; mi++)
                #pragma unroll
                for (int ni = 0; ni < NB; ni++)
                    acc[mi][ni] = __builtin_amdgcn_mfma_f32_16x16x32_bf16(afr[mi], bfr[ni], acc[mi][ni], 0, 0, 0);
            __builtin_amdgcn_s_setprio(0);
        }

        SCHED_FENCE();
        __builtin_amdgcn_s_barrier();
        SCHED_FENCE();
        bcur = bcur < 2 ? bcur + 1 : 0;
    }
    #undef ST64

    const long coff = PARTIAL ? (long)sp * GM * 64 * N : 0;
    #pragma unroll
    for (int mi = 0; mi < 2; mi++)
        #pragma unroll
        for (int ni = 0; ni < NB; ni++) {
            int col = n0 + wc * (BN / 2) + ni * 16 + lo;
            float bv = (!PARTIAL && bias) ? bias[col] : 0.f;
            #pragma unroll
            for (int rr = 0; rr < 4; rr++) {
                int row = m0 + wr * 32 + mi * 16 + hi * 4 + rr;
                float v = acc[mi][ni][rr] + bv;
                if (ACT) v = gelu_f(v);
                if (OUTBF16) ((__bf16*)C)[(long)row * N + col] = (__bf16)v;
                else         ((float*)C)[coff + (long)row * N + col] = v;
            }
        }
}

// ---------- fallback 64x64 GEMM (BK=32) ----------
template<int OUTBF16, int ACT, int RES>
__global__ __launch_bounds__(256) void gemm_bb(
    const __bf16* __restrict__ A, const __bf16* __restrict__ Bt,
    const float* __restrict__ bias, const float* __restrict__ res,
    void* __restrict__ C, int N, int K)
{
    __shared__ __bf16 As[64 * 32];
    __shared__ __bf16 Bs[64 * 32];
    const int t = threadIdx.x;
    const int m0 = blockIdx.x * 64;
    const int n0 = blockIdx.y * 64;
    const int w = t >> 6, lane = t & 63;
    const int lo = lane & 15, hi = lane >> 4;
    const int wr = w >> 1, wc = w & 1;

    f32x4 acc[2][2] = {};

    for (int k0 = 0; k0 < K; k0 += 32) {
        __syncthreads();
        GLDS16(A  + (long)(m0 + (t >> 2)) * K + k0 + ((t & 3) << 3), &As[t * 8]);
        GLDS16(Bt + (long)(n0 + (t >> 2)) * K + k0 + ((t & 3) << 3), &Bs[t * 8]);
        __syncthreads();
        bf16x8 afr[2], bfr[2];
        #pragma unroll
        for (int mi = 0; mi < 2; mi++)
            afr[mi] = *reinterpret_cast<const bf16x8*>(&As[(wr * 32 + mi * 16 + lo) * 32 + hi * 8]);
        #pragma unroll
        for (int ni = 0; ni < 2; ni++)
            bfr[ni] = *reinterpret_cast<const bf16x8*>(&Bs[(wc * 32 + ni * 16 + lo) * 32 + hi * 8]);
        #pragma unroll
        for (int mi = 0; mi < 2; mi++)
            #pragma unroll
            for (int ni = 0; ni < 2; ni++)
                acc[mi][ni] = __builtin_amdgcn_mfma_f32_16x16x32_bf16(afr[mi], bfr[ni], acc[mi][ni], 0, 0, 0);
    }

    #pragma unroll
    for (int mi = 0; mi < 2; mi++)
        #pragma unroll
        for (int ni = 0; ni < 2; ni++) {
            int col = n0 + wc * 32 + ni * 16 + lo;
            float bv = bias ? bias[col] : 0.f;
            #pragma unroll
            for (int rr = 0; rr < 4; rr++) {
                int row = m0 + wr * 32 + mi * 16 + hi * 4 + rr;
                float v = acc[mi][ni][rr] + bv;
                if (ACT) v = gelu_f(v);
                if (RES) v += res[(long)row * N + col];
                if (OUTBF16) ((__bf16*)C)[(long)row * N + col] = (__bf16)v;
                else         ((float*)C)[(long)row * N + col] = v;
            }
        }
}

// ---------- LM head fallback: A bf16 (glds), Wt[N][K] fp32 reg-staged ----------
__global__ __launch_bounds__(256) void gemm_lm(
    const __bf16* __restrict__ A, const float* __restrict__ Wt,
    float* __restrict__ C, int N, int K)
{
    __shared__ __bf16 As[128 * 32];
    __shared__ __bf16 Bs[128 * 32];
    const int t = threadIdx.x;
    const int m0 = blockIdx.x * 128;
    const int n0 = blockIdx.y * 128;
    const int w = t >> 6, lane = t & 63;
    const int lo = lane & 15, hi = lane >> 4;
    const int wr = w >> 1, wc = w & 1;

    f32x4 acc[4][4] = {};

    for (int k0 = 0; k0 < K; k0 += 32) {
        __syncthreads();
        #pragma unroll
        for (int i = 0; i < 2; i++) {
            int c = i * 256 + t;
            GLDS16(A + (long)(m0 + (c >> 2)) * K + k0 + ((c & 3) << 3), &As[c * 8]);
        }
        #pragma unroll
        for (int i = 0; i < 2; i++) {
            int c = i * 256 + t;
            int nr = n0 + (c >> 2);
            bf16x8 bv;
            if (nr < N) {
                const float* wp = Wt + (long)nr * K + k0 + ((c & 3) << 3);
                float4 b0 = *reinterpret_cast<const float4*>(wp);
                float4 b1 = *reinterpret_cast<const float4*>(wp + 4);
                bv[0] = (__bf16)b0.x; bv[1] = (__bf16)b0.y; bv[2] = (__bf16)b0.z; bv[3] = (__bf16)b0.w;
                bv[4] = (__bf16)b1.x; bv[5] = (__bf16)b1.y; bv[6] = (__bf16)b1.z; bv[7] = (__bf16)b1.w;
            } else {
                #pragma unroll
                for (int qq = 0; qq < 8; qq++) bv[qq] = (__bf16)0.f;
            }
            *reinterpret_cast<bf16x8*>(&Bs[c * 8]) = bv;
        }
        __syncthreads();
        bf16x8 afr[4], bfr[4];
        #pragma unroll
        for (int mi = 0; mi < 4; mi++)
            afr[mi] = *reinterpret_cast<const bf16x8*>(&As[(wr * 64 + mi * 16 + lo) * 32 + hi * 8]);
        #pragma unroll
        for (int ni = 0; ni < 4; ni++)
            bfr[ni] = *reinterpret_cast<const bf16x8*>(&Bs[(wc * 64 + ni * 16 + lo) * 32 + hi * 8]);
        #pragma unroll
        for (int mi = 0; mi < 4; mi++)
            #pragma unroll
            for (int ni = 0; ni < 4; ni++)
                acc[mi][ni] = __builtin_amdgcn_mfma_f32_16x16x32_bf16(afr[mi], bfr[ni], acc[mi][ni], 0, 0, 0);
    }

    #pragma unroll
    for (int mi = 0; mi < 4; mi++)
        #pragma unroll
        for (int ni = 0; ni < 4; ni++) {
            int col = n0 + wc * 64 + ni * 16 + lo;
            if (col < N) {
                #pragma unroll
                for (int rr = 0; rr < 4; rr++) {
                    int row = m0 + wr * 64 + mi * 16 + hi * 4 + rr;
                    C[(long)row * N + col] = acc[mi][ni][rr];
                }
            }
        }
}

// ---------- merged: attention (blocks 0..255) + aux BW work (blocks >= 256) ----------
__global__ __launch_bounds__(256) void attn_aux(
    const __bf16* __restrict__ qkv,
    const float* __restrict__ imgk, const float* __restrict__ imgv,
    const float* __restrict__ amask, __bf16* __restrict__ out,
    int aux_mode,
    const float* __restrict__ Wa, const float* __restrict__ Wp,
    const float* __restrict__ Wf, const float* __restrict__ Wf2,
    __bf16* __restrict__ oa, __bf16* __restrict__ op,
    __bf16* __restrict__ of, __bf16* __restrict__ of2,
    const float* __restrict__ wte, __bf16* __restrict__ wteb, long nvalid)
{
    __shared__ __align__(16) char smem[28416];
    const int bid = blockIdx.x;
    if (bid >= 256) {
        if (aux_mode == 1)
            tcvt_body(bid - 256, Wa, Wp, Wf, Wf2, oa, op, of, of2, (float*)smem);
        else
            wcvt_body(bid - 256, wte, wteb, nvalid);
        return;
    }

    __bf16 (*Ks)[72] = (__bf16(*)[72])(smem);
    __bf16 (*Vt)[72] = (__bf16(*)[72])(smem + 9216);
    __bf16 (*Ps)[16][72] = (__bf16(*)[16][72])(smem + 18432);
    float* kimg_s = (float*)(smem + 27648);
    float* amv_s  = (float*)(smem + 27904);

    const int qb = bid & 7;
    const int h  = (bid >> 3) & 15;
    const int b  = bid >> 7;
    const int t = threadIdx.x, w = t >> 6, lane = t & 63;
    const int lo = lane & 15, hi = lane >> 4;

    const int kr8 = t >> 2, kd8 = (t & 3) * 16;
    const int vr8 = t & 63, vd8 = (t >> 6) * 16;

    const __bf16* qrow = qkv + (long)(b * 512 + qb * 64 + w * 16 + lo) * 3072 + h * 64;
    bf16x8 qf0 = *reinterpret_cast<const bf16x8*>(qrow + hi * 8);
    bf16x8 qf1 = *reinterpret_cast<const bf16x8*>(qrow + 32 + hi * 8);

    if (t < 64) kimg_s[t] = imgk[b * 1024 + h * 64 + t];
    __syncthreads();

    float simg = 0.f;
    #pragma unroll
    for (int i = 0; i < 8; i++)
        simg += (float)qf0[i] * kimg_s[hi * 8 + i] + (float)qf1[i] * kimg_s[32 + hi * 8 + i];
    simg += __shfl_xor(simg, 16);
    simg += __shfl_xor(simg, 32);
    simg *= 0.125f;

    float pimg[4], l_part[4];
    f32x4 o_acc[4];
    #pragma unroll
    for (int rr = 0; rr < 4; rr++) {
        pimg[rr] = __expf(__shfl(simg, hi * 4 + rr));
        l_part[rr] = 0.f;
    }
    #pragma unroll
    for (int df = 0; df < 4; df++) {
        float vi = imgv[b * 1024 + h * 64 + df * 16 + lo];
        #pragma unroll
        for (int rr = 0; rr < 4; rr++) o_acc[df][rr] = pimg[rr] * vi;
    }

    bf16x8 ck0, ck1, cv0, cv1;
    {
        const __bf16* ks = qkv + (long)(b * 512 + kr8) * 3072 + 1024 + h * 64 + kd8;
        ck0 = *reinterpret_cast<const bf16x8*>(ks);
        ck1 = *reinterpret_cast<const bf16x8*>(ks + 8);
        const __bf16* vs = qkv + (long)(b * 512 + vr8) * 3072 + 2048 + h * 64 + vd8;
        cv0 = *reinterpret_cast<const bf16x8*>(vs);
        cv1 = *reinterpret_cast<const bf16x8*>(vs + 8);
    }

    for (int kb = 0; kb <= qb; kb++) {
        bf16x8 nk0, nk1, nv0, nv1;
        const bool more = (kb < qb);
        if (more) {
            const __bf16* ks = qkv + (long)(b * 512 + (kb + 1) * 64 + kr8) * 3072 + 1024 + h * 64 + kd8;
            nk0 = *reinterpret_cast<const bf16x8*>(ks);
            nk1 = *reinterpret_cast<const bf16x8*>(ks + 8);
            const __bf16* vs = qkv + (long)(b * 512 + (kb + 1) * 64 + vr8) * 3072 + 2048 + h * 64 + vd8;
            nv0 = *reinterpret_cast<const bf16x8*>(vs);
            nv1 = *reinterpret_cast<const bf16x8*>(vs + 8);
        }
        __syncthreads();
        *reinterpret_cast<bf16x8*>(&Ks[kr8][kd8])     = ck0;
        *reinterpret_cast<bf16x8*>(&Ks[kr8][kd8 + 8]) = ck1;
        #pragma unroll
        for (int i = 0; i < 8; i++) { Vt[vd8 + i][vr8] = cv0[i]; Vt[vd8 + 8 + i][vr8] = cv1[i]; }
        if (t < 64) amv_s[t] = (1.0f - amask[b * 512 + kb * 64 + t]) * -10000.0f;
        __syncthreads();

        f32x4 sf[4];
        #pragma unroll
        for (int js = 0; js < 4; js++) {
            bf16x8 kf0 = *reinterpret_cast<const bf16x8*>(&Ks[js * 16 + lo][hi * 8]);
            bf16x8 kf1 = *reinterpret_cast<const bf16x8*>(&Ks[js * 16 + lo][32 + hi * 8]);
            f32x4 a = {};
            a = __builtin_amdgcn_mfma_f32_16x16x32_bf16(qf0, kf0, a, 0, 0, 0);
            a = __builtin_amdgcn_mfma_f32_16x16x32_bf16(qf1, kf1, a, 0, 0, 0);
            sf[js] = a;
        }
        #pragma unroll
        for (int js = 0; js < 4; js++) {
            float amv = amv_s[js * 16 + lo];
            #pragma unroll
            for (int rr = 0; rr < 4; rr++) {
                float sv = sf[js][rr] * 0.125f + amv;
                if (kb == qb) {
                    int qrw = w * 16 + hi * 4 + rr;
                    if (js * 16 + lo > qrw) sv = -10000.0f + amv;
                }
                float p = __expf(sv);
                l_part[rr] += p;
                Ps[w][hi * 4 + rr][js * 16 + lo] = (__bf16)p;
            }
        }
        #pragma unroll
        for (int jb = 0; jb < 2; jb++) {
            bf16x8 pf = *reinterpret_cast<const bf16x8*>(&Ps[w][lo][jb * 32 + hi * 8]);
            #pragma unroll
            for (int df = 0; df < 4; df++) {
                bf16x8 vf = *reinterpret_cast<const bf16x8*>(&Vt[df * 16 + lo][jb * 32 + hi * 8]);
                o_acc[df] = __builtin_amdgcn_mfma_f32_16x16x32_bf16(pf, vf, o_acc[df], 0, 0, 0);
            }
        }
        if (more) { ck0 = nk0; ck1 = nk1; cv0 = nv0; cv1 = nv1; }
    }

    float linv[4];
    #pragma unroll
    for (int rr = 0; rr < 4; rr++) {
        float ls = l_part[rr];
        #pragma unroll
        for (int off = 1; off < 16; off <<= 1) ls += __shfl_xor(ls, off);
        linv[rr] = 1.0f / (pimg[rr] + ls);
    }
    #pragma unroll
    for (int df = 0; df < 4; df++)
        #pragma unroll
        for (int rr = 0; rr < 4; rr++) {
            long row = b * 512 + qb * 64 + w * 16 + hi * 4 + rr;
            out[row * 1024 + h * 64 + df * 16 + lo] = (__bf16)(o_acc[df][rr] * linv[rr]);
        }
}

// ---------- host orchestration ----------
extern "C" void kernel_launch(void* const* d_in, const int* in_sizes, int n_in,
                              void* d_out, int out_size, void* d_ws, size_t ws_size,
                              hipStream_t stream) {
    (void)in_sizes; (void)n_in; (void)out_size;
    const int*   ids   = (const int*)d_in[0];
    const float* amask = (const float*)d_in[1];
    const float* ihs   = (const float*)d_in[2];
    const float* wte   = (const float*)d_in[3];
    const float* ftW1  = (const float*)d_in[4];
    const float* ftb1  = (const float*)d_in[5];
    const float* ftW2  = (const float*)d_in[6];
    const float* ftb2  = (const float*)d_in[7];
    const float* ln1g  = (const float*)d_in[8];
    const float* ln1b  = (const float*)d_in[9];
    const float* Wattn = (const float*)d_in[10];
    const float* battn = (const float*)d_in[11];
    const float* Wuk   = (const float*)d_in[12];
    const float* buk   = (const float*)d_in[13];
    const float* Wuv   = (const float*)d_in[14];
    const float* buv   = (const float*)d_in[15];
    const float* Wproj = (const float*)d_in[16];
    const float* bproj = (const float*)d_in[17];
    const float* ln2g  = (const float*)d_in[18];
    const float* ln2b  = (const float*)d_in[19];
    const float* Wfc   = (const float*)d_in[20];
    const float* bfc   = (const float*)d_in[21];
    const float* Wfc2  = (const float*)d_in[22];
    const float* bfc2  = (const float*)d_in[23];
    const float* lnfg  = (const float*)d_in[24];
    const float* lnfb  = (const float*)d_in[25];
    float* out = (float*)d_out;

    const long VP2 = 50432;              // V padded to multiple of 256
    const long NVALID = 50257L * 1024;
    char* base = (char*)d_ws;
    float* ftmp  = (float*)(base);
    float* img   = (float*)(base + (1 << 13));
    float* imgk  = (float*)(base + (1 << 14));
    float* imgv  = (float*)(base + 114688);
    float* part  = (float*)(base + 212992);
    float* h     = (float*)(base + 1048576);
    char* p = base + 5 * 1048576;
    __bf16* xb    = (__bf16*)p; p += 2 * 1048576;
    __bf16* qkvb  = (__bf16*)p; p += 6 * 1048576;
    __bf16* attob = (__bf16*)p; p += 2 * 1048576;
    __bf16* ffb   = (__bf16*)p; p += 8 * 1048576;
    __bf16* wtA0  = (__bf16*)p; p += 6 * 1048576;
    __bf16* wtP0  = (__bf16*)p; p += 2 * 1048576;
    __bf16* wtF0  = (__bf16*)p; p += 8 * 1048576;
    __bf16* wtF20 = (__bf16*)p; p += 8 * 1048576;
    __bf16* wteb  = (__bf16*)p; p += VP2 * 1024 * 2;
    size_t need1 = (size_t)(p - base);
    float* part_g = (float*)(base + need1);
    size_t need2 = need1 + 4 * 1048576 * sizeof(float);
    char* p2 = base + need2;
    __bf16* wtA1  = (__bf16*)p2; p2 += 6 * 1048576;
    __bf16* wtP1  = (__bf16*)p2; p2 += 2 * 1048576;
    __bf16* wtF1  = (__bf16*)p2; p2 += 8 * 1048576;
    __bf16* wtF21 = (__bf16*)p2; p2 += 8 * 1048576;
    size_t need3 = (size_t)(p2 - base);
    const bool big1 = (ws_size >= need1);
    const bool big2 = (ws_size >= need2);
    const bool big3 = (ws_size >= need3);

    __bf16* wtA_s[2]  = {wtA0, wtA1};
    __bf16* wtP_s[2]  = {wtP0, wtP1};
    __bf16* wtF_s[2]  = {wtF0, wtF1};
    __bf16* wtF2_s[2] = {wtF20, wtF21};

    dim3 b256(256);

    // pre-loop: union (embed+ln10 | tcvt layer0 | ft1 partial) then the serial gemv chain
    preloop0<<<dim3(4224), b256, 0, stream>>>(
        ids, wte, h, xb, ln1g, ln1b,
        Wattn, Wproj, Wfc, Wfc2, wtA0, wtP0, wtF0, wtF20,
        ihs, ftW1, part);
    gemv_reduce<<<dim3(8), b256, 0, stream>>>(part, ftb1, 0, ftmp, 1024, 1, 1);
    gemv_part<<<dim3(16, 8, 1), b256, 0, stream>>>(ftmp, 1024, ftW2, 0, part, 1024, 1024);
    gemv_reduce<<<dim3(8), b256, 0, stream>>>(part, ftb2, 0, img, 1024, 1, 0);
    gemv_kv_part<<<dim3(16, 4, 24), b256, 0, stream>>>(img, Wuk, Wuv, part);
    gemv_kv_reduce<<<dim3(192), b256, 0, stream>>>(part, buk, buv, imgk, imgv);

    for (int l = 0; l < 12; l++) {
        const int cs = big3 ? (l & 1) : 0;
        __bf16* cA  = wtA_s[cs];
        __bf16* cP  = wtP_s[cs];
        __bf16* cF  = wtF_s[cs];
        __bf16* cF2 = wtF2_s[cs];

        if (!big3 && l > 0) {
            tcvt_std<<<dim3(3072), b256, 0, stream>>>(
                Wattn + (long)l * 1024 * 3072, Wproj + (long)l * 1024 * 1024,
                Wfc + (long)l * 1024 * 4096, Wfc2 + (long)l * 4096 * 1024,
                wtA0, wtP0, wtF0, wtF20);
        }

        gemm64<128, 1, 0, 0><<<dim3(384), b256, 0, stream>>>(
            xb, cA, battn + l * 3072, qkvb, 3072, 1024, 16, 24, 1);

        if (big3 && l < 11) {
            const int ns = (l + 1) & 1;
            attn_aux<<<dim3(256 + 3072), b256, 0, stream>>>(
                qkvb, imgk + l * 2048, imgv + l * 2048, amask, attob, 1,
                Wattn + (long)(l + 1) * 1024 * 3072, Wproj + (long)(l + 1) * 1024 * 1024,
                Wfc + (long)(l + 1) * 1024 * 4096, Wfc2 + (long)(l + 1) * 4096 * 1024,
                wtA_s[ns], wtP_s[ns], wtF_s[ns], wtF2_s[ns],
                nullptr, nullptr, 0);
        } else if (big3 && l == 11) {
            attn_aux<<<dim3(256 + 6304), b256, 0, stream>>>(
                qkvb, imgk + l * 2048, imgv + l * 2048, amask, attob, 2,
                nullptr, nullptr, nullptr, nullptr,
                nullptr, nullptr, nullptr, nullptr,
                wte, wteb, NVALID);
        } else {
            attn_aux<<<dim3(256), b256, 0, stream>>>(
                qkvb, imgk + l * 2048, imgv + l * 2048, amask, attob, 0,
                nullptr, nullptr, nullptr, nullptr,
                nullptr, nullptr, nullptr, nullptr,
                nullptr, nullptr, 0);
        }

        const float* ng = (l < 11) ? (ln1g + (l + 1) * 1024) : lnfg;
        const float* nb = (l < 11) ? (ln1b + (l + 1) * 1024) : lnfb;
        if (big2) {
            gemm64<64, 0, 0, 1><<<dim3(512), b256, 0, stream>>>(
                attob, cP, nullptr, part_g, 1024, 1024, 16, 16, 2);
            lnadd_k<2><<<dim3(1024), b256, 0, stream>>>(
                h, part_g, bproj + l * 1024, ln2g + l * 1024, ln2b + l * 1024, xb);
            gemm64<128, 1, 1, 0><<<dim3(512), b256, 0, stream>>>(
                xb, cF, bfc + l * 4096, ffb, 4096, 1024, 16, 32, 1);
            gemm64<128, 0, 0, 1><<<dim3(512), b256, 0, stream>>>(
                ffb, cF2, nullptr, part_g, 1024, 4096, 16, 8, 4);
            lnadd_k<4><<<dim3(1024), b256, 0, stream>>>(
                h, part_g, bfc2 + l * 1024, ng, nb, xb);
        } else {
            gemm_bb<0, 0, 1><<<dim3(16, 16), b256, 0, stream>>>(
                attob, cP, bproj + l * 1024, h, h, 1024, 1024);
            ln_k<<<dim3(1024), b256, 0, stream>>>(h, xb, ln2g + l * 1024, ln2b + l * 1024);
            gemm64<128, 1, 1, 0><<<dim3(512), b256, 0, stream>>>(
                xb, cF, bfc + l * 4096, ffb, 4096, 1024, 16, 32, 1);
            gemm_bb<0, 0, 1><<<dim3(16, 16), b256, 0, stream>>>(
                ffb, cF2, bfc2 + l * 1024, h, h, 1024, 4096);
            ln_k<<<dim3(1024), b256, 0, stream>>>(h, xb, ng, nb);
        }
    }

    // xb holds lnf(h)
    if (big1) {
        if (!big3)
            wcvt_std<<<dim3((unsigned)(VP2 * 1024 / 8192)), b256, 0, stream>>>(wte, wteb, NVALID);
        gemm_lm8<<<dim3(4 * (int)(VP2 / 256)), dim3(512), 0, stream>>>(
            xb, wteb, out, 50257, 1024, 4, (int)(VP2 / 256));
    } else {
        gemm_lm<<<dim3(8, 393), b256, 0, stream>>>(xb, wte, out, 50257, 1024);
    }
}